// Round 2
// baseline (10920.943 us; speedup 1.0000x reference)
//
#include <hip/hip_runtime.h>

#define BN_ROWS 65536
#define DIMX 256
#define CDIM 1024
#define KCODES 4096

// ---------------- ws layout (bytes) — fixed region ~5.8 MB ----------------
static const size_t OFF_ESQ = 0;            // 4096 f32
static const size_t OFF_ZSQ = 16384;        // 65536 f32
static const size_t OFF_IDX1 = 278528;      // 65536 i32
static const size_t OFF_IDX2 = 540672;      // 65536 i32
static const size_t OFF_S1 = 802816;        // 65536 f32
static const size_t OFF_S2 = 1064960;       // 65536 f32
static const size_t OFF_CROW = 1327104;     // 65536 f32
static const size_t OFF_EPOST = 1589248;    // 4096*256 f32 = 4 MB
static const size_t OFF_ZE = 5783552;       // chunk buffer: chunk_rows*1024 f32

#define FLT_BIG 3.402823466e+38f

// ---------------- K0: e_sq ----------------
__global__ __launch_bounds__(256) void k_esq(const float* __restrict__ embed,
                                             float* __restrict__ e_sq) {
  const int t = threadIdx.x, wv = t >> 6, lane = t & 63;
  const int row = blockIdx.x * 4 + wv;
  const float* e = embed + (size_t)row * CDIM;
  float s = 0.f;
  for (int k = lane * 4; k < CDIM; k += 256) {
    float4 v = *(const float4*)(e + k);
    s = fmaf(v.x, v.x, s); s = fmaf(v.y, v.y, s);
    s = fmaf(v.z, v.z, s); s = fmaf(v.w, v.w, s);
  }
#pragma unroll
  for (int o = 32; o > 0; o >>= 1) s += __shfl_xor(s, o);
  if (lane == 0) e_sq[row] = s;
}

// ---------------- K1: LN + GELU + @w_pre -> z_e chunk (+ z_sq) ----------------
__global__ __launch_bounds__(256) void k_ln_gelu_gemm(
    const float* __restrict__ x, const float* __restrict__ ln_g,
    const float* __restrict__ ln_b, const float* __restrict__ w_pre,
    const float* __restrict__ b_pre, float* __restrict__ z_e,
    float* __restrict__ z_sq, int row0) {
  __shared__ float g[16][DIMX];
  const int t = threadIdx.x;
  const int lrow0 = blockIdx.x * 16;          // local (chunk) row base
  const int grow0 = row0 + lrow0;             // global row base
  const int wv = t >> 6, lane = t & 63;
#pragma unroll
  for (int j = 0; j < 4; ++j) {
    const int r = wv * 4 + j;
    const float* xr = x + (size_t)(grow0 + r) * DIMX;
    float4 v = *(const float4*)(xr + lane * 4);
    float s = v.x + v.y + v.z + v.w;
    float ss = v.x * v.x + v.y * v.y + v.z * v.z + v.w * v.w;
#pragma unroll
    for (int o = 32; o > 0; o >>= 1) { s += __shfl_xor(s, o); ss += __shfl_xor(ss, o); }
    const float mu = s * (1.0f / 256.0f);
    const float var = ss * (1.0f / 256.0f) - mu * mu;
    const float rstd = rsqrtf(var + 1e-5f);
    float vv[4] = {v.x, v.y, v.z, v.w};
#pragma unroll
    for (int q = 0; q < 4; ++q) {
      const int d = lane * 4 + q;
      float xn = (vv[q] - mu) * rstd * ln_g[d] + ln_b[d];
      g[r][d] = 0.5f * xn * (1.0f + erff(xn * 0.70710678118654752f));
    }
  }
  __syncthreads();
  float acc[16][4];
#pragma unroll
  for (int r = 0; r < 16; ++r)
#pragma unroll
    for (int c = 0; c < 4; ++c) acc[r][c] = 0.f;
#pragma unroll 4
  for (int d = 0; d < DIMX; ++d) {
    float4 w = *(const float4*)(w_pre + (size_t)d * CDIM + t * 4);
#pragma unroll
    for (int r = 0; r < 16; ++r) {
      const float gv = g[r][d];
      acc[r][0] = fmaf(gv, w.x, acc[r][0]);
      acc[r][1] = fmaf(gv, w.y, acc[r][1]);
      acc[r][2] = fmaf(gv, w.z, acc[r][2]);
      acc[r][3] = fmaf(gv, w.w, acc[r][3]);
    }
  }
  float4 bp = *(const float4*)(b_pre + t * 4);
  float ps[16];
#pragma unroll
  for (int r = 0; r < 16; ++r) {
    float4 o;
    o.x = acc[r][0] + bp.x; o.y = acc[r][1] + bp.y;
    o.z = acc[r][2] + bp.z; o.w = acc[r][3] + bp.w;
    *(float4*)(z_e + (size_t)(lrow0 + r) * CDIM + t * 4) = o;
    ps[r] = o.x * o.x + o.y * o.y + o.z * o.z + o.w * o.w;
  }
  // per-row sum of squares across 256 threads
#pragma unroll
  for (int r = 0; r < 16; ++r)
#pragma unroll
    for (int o = 32; o > 0; o >>= 1) ps[r] += __shfl_xor(ps[r], o);
  __shared__ float zps[4][16];
  if (lane == 0)
#pragma unroll
    for (int r = 0; r < 16; ++r) zps[wv][r] = ps[r];
  __syncthreads();
  if (t < 16) z_sq[grow0 + t] = zps[0][t] + zps[1][t] + zps[2][t] + zps[3][t];
}

// ---------------- K2: distance GEMM + top-2 argmin ----------------
#define K2_BM 128
#define K2_BN 64
#define K2_KC 32
#define AS_LD 132
#define BS_LD 68

__global__ __launch_bounds__(256) void k_argmin(
    const float* __restrict__ Z, const float* __restrict__ E,
    const float* __restrict__ e_sq, int* __restrict__ idx1o,
    int* __restrict__ idx2o, float* __restrict__ s1o, float* __restrict__ s2o,
    int row0) {
  __shared__ float smem[8192];  // 32 KB
  float* As = smem;                  // [32][132]
  float* Bs = smem + K2_KC * AS_LD;  // [32][68]
  const int t = threadIdx.x;
  const int lrow0 = blockIdx.x * K2_BM;
  const int tr = t >> 4, tc = t & 15;

  float s1[8], s2[8];
  int i1[8], i2[8];
#pragma unroll
  for (int i = 0; i < 8; ++i) {
    s1[i] = FLT_BIG; s2[i] = FLT_BIG; i1[i] = 0x7fffffff; i2[i] = 0x7fffffff;
  }

  for (int n0 = 0; n0 < KCODES; n0 += K2_BN) {
    float acc[8][4];
#pragma unroll
    for (int i = 0; i < 8; ++i)
#pragma unroll
      for (int j = 0; j < 4; ++j) acc[i][j] = 0.f;

    for (int k0 = 0; k0 < CDIM; k0 += K2_KC) {
      __syncthreads();
#pragma unroll
      for (int p = 0; p < 4; ++p) {
        const int fl = (p * 256 + t) * 4;
        const int r = fl >> 5, kk = fl & 31;
        float4 v = *(const float4*)(Z + (size_t)(lrow0 + r) * CDIM + k0 + kk);
        As[(kk + 0) * AS_LD + r] = v.x;
        As[(kk + 1) * AS_LD + r] = v.y;
        As[(kk + 2) * AS_LD + r] = v.z;
        As[(kk + 3) * AS_LD + r] = v.w;
      }
#pragma unroll
      for (int p = 0; p < 2; ++p) {
        const int fl = (p * 256 + t) * 4;
        const int c = fl >> 5, kk = fl & 31;
        float4 v = *(const float4*)(E + (size_t)(n0 + c) * CDIM + k0 + kk);
        Bs[(kk + 0) * BS_LD + c] = v.x;
        Bs[(kk + 1) * BS_LD + c] = v.y;
        Bs[(kk + 2) * BS_LD + c] = v.z;
        Bs[(kk + 3) * BS_LD + c] = v.w;
      }
      __syncthreads();
#pragma unroll
      for (int kk = 0; kk < K2_KC; ++kk) {
        const float4 a0 = *(const float4*)(As + kk * AS_LD + tr * 8);
        const float4 a1 = *(const float4*)(As + kk * AS_LD + tr * 8 + 4);
        const float4 b = *(const float4*)(Bs + kk * BS_LD + tc * 4);
        const float av[8] = {a0.x, a0.y, a0.z, a0.w, a1.x, a1.y, a1.z, a1.w};
        const float bv[4] = {b.x, b.y, b.z, b.w};
#pragma unroll
        for (int i = 0; i < 8; ++i)
#pragma unroll
          for (int j = 0; j < 4; ++j) acc[i][j] = fmaf(av[i], bv[j], acc[i][j]);
      }
    }
#pragma unroll
    for (int j = 0; j < 4; ++j) {
      const int c = n0 + tc * 4 + j;
      const float es = e_sq[c];
#pragma unroll
      for (int i = 0; i < 8; ++i) {
        const float s = fmaf(-2.0f, acc[i][j], es);
        if (s < s1[i]) {
          s2[i] = s1[i]; i2[i] = i1[i]; s1[i] = s; i1[i] = c;
        } else if (s < s2[i]) {
          s2[i] = s; i2[i] = c;
        }
      }
    }
  }
  __syncthreads();
  float* rs = smem;               // [128][16][2]
  int* ri = (int*)(smem + 4096);  // [128][16][2]
#pragma unroll
  for (int i = 0; i < 8; ++i) {
    const int r = tr * 8 + i;
    rs[(r * 16 + tc) * 2 + 0] = s1[i];
    rs[(r * 16 + tc) * 2 + 1] = s2[i];
    ri[(r * 16 + tc) * 2 + 0] = i1[i];
    ri[(r * 16 + tc) * 2 + 1] = i2[i];
  }
  __syncthreads();
  if (t < K2_BM) {
    float b1 = FLT_BIG, b2 = FLT_BIG;
    int j1 = 0x7fffffff, j2 = 0x7fffffff;
    for (int c = 0; c < 32; ++c) {
      const float s = rs[t * 32 + c];
      const int ix = ri[t * 32 + c];
      if (s < b1 || (s == b1 && ix < j1)) {
        b2 = b1; j2 = j1; b1 = s; j1 = ix;
      } else if (s < b2 || (s == b2 && ix < j2)) {
        b2 = s; j2 = ix;
      }
    }
    const int g = row0 + lrow0 + t;
    s1o[g] = b1; s2o[g] = b2;
    idx1o[g] = j1; idx2o[g] = j2;
  }
}

// ---------------- K2b: f64 rescore of near-tie top-2 + commit_row ----------------
#define MARGIN 0.05f
__global__ __launch_bounds__(256) void k_rescore(
    const float* __restrict__ Z, const float* __restrict__ E,
    int* __restrict__ idx1, const int* __restrict__ idx2,
    const float* __restrict__ s1a, const float* __restrict__ s2a,
    const float* __restrict__ z_sq, float* __restrict__ crow,
    float* __restrict__ out_idx, int row0) {
  const int t = threadIdx.x, wv = t >> 6, lane = t & 63;
  const int lbase = (blockIdx.x * 4 + wv) * 64;
  for (int rr = 0; rr < 64; ++rr) {
    const int lrow = lbase + rr;
    const int grow = row0 + lrow;
    const float s1 = s1a[grow], s2 = s2a[grow];
    int fin = idx1[grow];
    float cval = z_sq[grow] + s1;  // ||z-e||^2 via identity
    if (s2 - s1 < MARGIN) {
      const int a = fin, b = idx2[grow];
      const float* z = Z + (size_t)lrow * CDIM;
      const float* ea = E + (size_t)a * CDIM;
      const float* eb = E + (size_t)b * CDIM;
      double d1 = 0.0, d2 = 0.0;
      for (int k = lane; k < CDIM; k += 64) {
        const double zv = (double)z[k];
        const double u = zv - (double)ea[k]; d1 += u * u;
        const double v = zv - (double)eb[k]; d2 += v * v;
      }
#pragma unroll
      for (int o = 32; o > 0; o >>= 1) {
        d1 += __shfl_xor(d1, o);
        d2 += __shfl_xor(d2, o);
      }
      if (d2 < d1 || (d2 == d1 && b < a)) { fin = b; d1 = d2; }
      cval = (float)d1;
    }
    if (lane == 0) {
      idx1[grow] = fin;
      out_idx[grow] = (float)fin;
      crow[grow] = cval;
    }
  }
}

// ---------------- K4: E_post = embed @ w_post ----------------
__global__ __launch_bounds__(256) void k_epost(const float* __restrict__ E,
                                               const float* __restrict__ w_post,
                                               float* __restrict__ E_post) {
  __shared__ float es[16][128];
  const int t = threadIdx.x;
  const int r0 = blockIdx.x * 16;
  float acc[16];
#pragma unroll
  for (int r = 0; r < 16; ++r) acc[r] = 0.f;
  for (int k0 = 0; k0 < CDIM; k0 += 128) {
    __syncthreads();
#pragma unroll
    for (int p = 0; p < 2; ++p) {
      const int fl = (p * 256 + t) * 4;
      const int r = fl >> 7, kk = fl & 127;
      float4 v = *(const float4*)(E + (size_t)(r0 + r) * CDIM + k0 + kk);
      *(float4*)&es[r][kk] = v;
    }
    __syncthreads();
#pragma unroll 4
    for (int d = 0; d < 128; ++d) {
      const float w = w_post[(size_t)(k0 + d) * DIMX + t];
#pragma unroll
      for (int r = 0; r < 16; ++r) acc[r] = fmaf(es[r][d], w, acc[r]);
    }
  }
#pragma unroll
  for (int r = 0; r < 16; ++r)
    E_post[(size_t)(r0 + r) * DIMX + t] = acc[r];
}

// ---------------- K5: gather E_post rows + bias ----------------
__global__ __launch_bounds__(256) void k_gather(const float* __restrict__ E_post,
                                                const int* __restrict__ idx,
                                                const float* __restrict__ b_post,
                                                float* __restrict__ outq) {
  const int t = threadIdx.x;
  const int r0 = blockIdx.x * 16;
  const float bp = b_post[t];
#pragma unroll
  for (int i = 0; i < 16; ++i) {
    const int row = r0 + i;
    outq[(size_t)row * DIMX + t] = E_post[(size_t)idx[row] * DIMX + t] + bp;
  }
}

// ---------------- K6: commit reduce (single block, f64) ----------------
__global__ __launch_bounds__(256) void k_commit_final(
    const float* __restrict__ crow, float* __restrict__ out_commit) {
  const int t = threadIdx.x;
  double s = 0.0;
  for (int i = t; i < BN_ROWS; i += 256) s += (double)crow[i];
#pragma unroll
  for (int o = 32; o > 0; o >>= 1) s += __shfl_xor(s, o);
  __shared__ double wsum[4];
  if ((t & 63) == 0) wsum[t >> 6] = s;
  __syncthreads();
  if (t == 0)
    *out_commit =
        (float)(0.25 * (wsum[0] + wsum[1] + wsum[2] + wsum[3]) /
                (65536.0 * 1024.0));
}

extern "C" void kernel_launch(void* const* d_in, const int* in_sizes, int n_in,
                              void* d_out, int out_size, void* d_ws,
                              size_t ws_size, hipStream_t stream) {
  const float* x = (const float*)d_in[0];
  const float* ln_g = (const float*)d_in[1];
  const float* ln_b = (const float*)d_in[2];
  const float* w_pre = (const float*)d_in[3];
  const float* b_pre = (const float*)d_in[4];
  const float* embed = (const float*)d_in[5];
  const float* w_post = (const float*)d_in[6];
  const float* b_post = (const float*)d_in[7];

  float* out = (float*)d_out;
  float* outq = out;                    // 16777216 f32
  float* out_idx = out + 16777216;      // 65536 f32
  float* out_commit = out + 16842752;   // 1 f32

  char* ws = (char*)d_ws;
  float* e_sq = (float*)(ws + OFF_ESQ);
  float* z_sq = (float*)(ws + OFF_ZSQ);
  int* idx1 = (int*)(ws + OFF_IDX1);
  int* idx2 = (int*)(ws + OFF_IDX2);
  float* s1a = (float*)(ws + OFF_S1);
  float* s2a = (float*)(ws + OFF_S2);
  float* crow = (float*)(ws + OFF_CROW);
  float* E_post = (float*)(ws + OFF_EPOST);
  float* z_e = (float*)(ws + OFF_ZE);

  // chunk rows sized to available workspace (power of 2, >=1024)
  size_t cap = (ws_size > OFF_ZE) ? (ws_size - OFF_ZE) / ((size_t)CDIM * 4) : 0;
  int chunk = 1024;
  while ((size_t)(chunk * 2) <= cap && chunk < BN_ROWS) chunk *= 2;

  k_esq<<<KCODES / 4, 256, 0, stream>>>(embed, e_sq);
  k_epost<<<KCODES / 16, 256, 0, stream>>>(embed, w_post, E_post);

  for (int row0 = 0; row0 < BN_ROWS; row0 += chunk) {
    k_ln_gelu_gemm<<<chunk / 16, 256, 0, stream>>>(x, ln_g, ln_b, w_pre, b_pre,
                                                   z_e, z_sq, row0);
    k_argmin<<<chunk / K2_BM, 256, 0, stream>>>(z_e, embed, e_sq, idx1, idx2,
                                                s1a, s2a, row0);
    k_rescore<<<chunk / 256, 256, 0, stream>>>(z_e, embed, idx1, idx2, s1a,
                                               s2a, z_sq, crow, out_idx, row0);
  }

  k_gather<<<BN_ROWS / 16, 256, 0, stream>>>(E_post, idx1, b_post, outq);
  k_commit_final<<<1, 256, 0, stream>>>(crow, out_commit);
}

// Round 3
// 6595.437 us; speedup vs baseline: 1.6558x; 1.6558x over previous
//
#include <hip/hip_runtime.h>

#define BN_ROWS 65536
#define DIMX 256
#define CDIM 1024
#define KCODES 4096
#define MARGIN 0.03f
#define FLT_BIG 3.402823466e+38f

// ---------------- ws layout (bytes) ----------------
static const size_t OFF_ESQ   = 0;          // 4096 f32 (16KB)
static const size_t OFF_ZSQ   = 16384;      // 65536 f32
static const size_t OFF_IDXF  = 278528;     // 65536 i32
static const size_t OFF_CROW  = 540672;     // 65536 f32
static const size_t OFF_EPOST = 802816;     // 4096*256 f32 (4MB)
static const size_t OFF_EH    = 4997120;    // 4096*1024 bf16 (8MB)
static const size_t OFF_EL    = 13385728;   // 4096*1024 bf16 (8MB)
static const size_t OFF_PART  = 21774336;   // 4 * chunk * 16B
// OFF_ZH = OFF_PART + chunk*64 ; OFF_ZL = OFF_ZH + chunk*2048

typedef __attribute__((ext_vector_type(8))) short bf16x8;
typedef __attribute__((ext_vector_type(4))) float f32x4;

#define GLOAD_LDS16(gsrc, ldst)                                                \
  __builtin_amdgcn_global_load_lds(                                            \
      (const __attribute__((address_space(1))) void*)(gsrc),                   \
      (__attribute__((address_space(3))) void*)(ldst), 16, 0, 0)

__device__ inline unsigned short bf_rtn(float f) {
  unsigned u = __float_as_uint(f);
  unsigned r = (u + 0x7FFFu + ((u >> 16) & 1u)) >> 16;
  return (unsigned short)r;
}
__device__ inline void bf_split(float f, unsigned short& h, unsigned short& l) {
  h = bf_rtn(f);
  float hf = __uint_as_float(((unsigned)h) << 16);
  l = bf_rtn(f - hf);
}
__device__ inline unsigned fkey(float s) {
  unsigned b = __float_as_uint(s);
  return b ^ ((unsigned)((int)b >> 31) | 0x80000000u);
}
__device__ inline float keyinv(unsigned k) {
  unsigned b = (k & 0x80000000u) ? (k ^ 0x80000000u) : ~k;
  return __uint_as_float(b);
}
__device__ inline void merge2(unsigned long long& a1, unsigned long long& a2,
                              unsigned long long b1, unsigned long long b2) {
  unsigned long long n1 = a1 < b1 ? a1 : b1;
  unsigned long long hi = a1 < b1 ? b1 : a1;
  unsigned long long m = a2 < b2 ? a2 : b2;
  a2 = hi < m ? hi : m;
  a1 = n1;
}

// ---------------- K0: e_sq ----------------
__global__ __launch_bounds__(256) void k_esq(const float* __restrict__ embed,
                                             float* __restrict__ e_sq) {
  const int t = threadIdx.x, wv = t >> 6, lane = t & 63;
  const int row = blockIdx.x * 4 + wv;
  const float* e = embed + (size_t)row * CDIM;
  float s = 0.f;
  for (int k = lane * 4; k < CDIM; k += 256) {
    float4 v = *(const float4*)(e + k);
    s = fmaf(v.x, v.x, s); s = fmaf(v.y, v.y, s);
    s = fmaf(v.z, v.z, s); s = fmaf(v.w, v.w, s);
  }
#pragma unroll
  for (int o = 32; o > 0; o >>= 1) s += __shfl_xor(s, o);
  if (lane == 0) e_sq[row] = s;
}

// ---------------- K0b: E -> hi/lo bf16 ----------------
__global__ __launch_bounds__(256) void k_ehilo(const float* __restrict__ embed,
                                               short* __restrict__ Eh,
                                               short* __restrict__ El) {
  const int t = threadIdx.x;
  const size_t row = blockIdx.x;
  float4 v = *(const float4*)(embed + row * CDIM + t * 4);
  unsigned short h0, l0, h1, l1, h2, l2, h3, l3;
  bf_split(v.x, h0, l0); bf_split(v.y, h1, l1);
  bf_split(v.z, h2, l2); bf_split(v.w, h3, l3);
  *(short4*)(Eh + row * CDIM + t * 4) =
      make_short4((short)h0, (short)h1, (short)h2, (short)h3);
  *(short4*)(El + row * CDIM + t * 4) =
      make_short4((short)l0, (short)l1, (short)l2, (short)l3);
}

// ---------------- K1: LN + GELU + @w_pre -> z hi/lo + z_sq ----------------
__global__ __launch_bounds__(256) void k_ln_gelu_gemm(
    const float* __restrict__ x, const float* __restrict__ ln_g,
    const float* __restrict__ ln_b, const float* __restrict__ w_pre,
    const float* __restrict__ b_pre, short* __restrict__ zh,
    short* __restrict__ zl, float* __restrict__ z_sq, int row0) {
  __shared__ float g[16][DIMX];
  const int t = threadIdx.x;
  const int lrow0 = blockIdx.x * 16;
  const int grow0 = row0 + lrow0;
  const int wv = t >> 6, lane = t & 63;
#pragma unroll
  for (int j = 0; j < 4; ++j) {
    const int r = wv * 4 + j;
    const float* xr = x + (size_t)(grow0 + r) * DIMX;
    float4 v = *(const float4*)(xr + lane * 4);
    float s = v.x + v.y + v.z + v.w;
    float ss = v.x * v.x + v.y * v.y + v.z * v.z + v.w * v.w;
#pragma unroll
    for (int o = 32; o > 0; o >>= 1) { s += __shfl_xor(s, o); ss += __shfl_xor(ss, o); }
    const float mu = s * (1.0f / 256.0f);
    const float var = ss * (1.0f / 256.0f) - mu * mu;
    const float rstd = rsqrtf(var + 1e-5f);
    float vv[4] = {v.x, v.y, v.z, v.w};
#pragma unroll
    for (int q = 0; q < 4; ++q) {
      const int d = lane * 4 + q;
      float xn = (vv[q] - mu) * rstd * ln_g[d] + ln_b[d];
      g[r][d] = 0.5f * xn * (1.0f + erff(xn * 0.70710678118654752f));
    }
  }
  __syncthreads();
  float acc[16][4];
#pragma unroll
  for (int r = 0; r < 16; ++r)
#pragma unroll
    for (int c = 0; c < 4; ++c) acc[r][c] = 0.f;
#pragma unroll 4
  for (int d = 0; d < DIMX; ++d) {
    float4 w = *(const float4*)(w_pre + (size_t)d * CDIM + t * 4);
#pragma unroll
    for (int r = 0; r < 16; ++r) {
      const float gv = g[r][d];
      acc[r][0] = fmaf(gv, w.x, acc[r][0]);
      acc[r][1] = fmaf(gv, w.y, acc[r][1]);
      acc[r][2] = fmaf(gv, w.z, acc[r][2]);
      acc[r][3] = fmaf(gv, w.w, acc[r][3]);
    }
  }
  float4 bp = *(const float4*)(b_pre + t * 4);
  float ps[16];
#pragma unroll
  for (int r = 0; r < 16; ++r) {
    float4 o;
    o.x = acc[r][0] + bp.x; o.y = acc[r][1] + bp.y;
    o.z = acc[r][2] + bp.z; o.w = acc[r][3] + bp.w;
    unsigned short h0, l0, h1, l1, h2, l2, h3, l3;
    bf_split(o.x, h0, l0); bf_split(o.y, h1, l1);
    bf_split(o.z, h2, l2); bf_split(o.w, h3, l3);
    *(short4*)(zh + (size_t)(lrow0 + r) * CDIM + t * 4) =
        make_short4((short)h0, (short)h1, (short)h2, (short)h3);
    *(short4*)(zl + (size_t)(lrow0 + r) * CDIM + t * 4) =
        make_short4((short)l0, (short)l1, (short)l2, (short)l3);
    ps[r] = o.x * o.x + o.y * o.y + o.z * o.z + o.w * o.w;
  }
#pragma unroll
  for (int r = 0; r < 16; ++r)
#pragma unroll
    for (int o = 32; o > 0; o >>= 1) ps[r] += __shfl_xor(ps[r], o);
  __shared__ float zps[4][16];
  if (lane == 0)
#pragma unroll
    for (int r = 0; r < 16; ++r) zps[wv][r] = ps[r];
  __syncthreads();
  if (t < 16) z_sq[grow0 + t] = zps[0][t] + zps[1][t] + zps[2][t] + zps[3][t];
}

// ---------------- K2: bf16x3 MFMA score GEMM + top-2 (per code-split) --------
// grid = (chunk/128)*4 ; block = 256 (4 waves, 2x2); LDS 32KB fragment-major
__global__ __launch_bounds__(256, 2) void k_score(
    const short* __restrict__ Eh, const short* __restrict__ El,
    const short* __restrict__ Zh, const short* __restrict__ Zl,
    const float* __restrict__ e_sq, unsigned long long* __restrict__ part,
    int chunk) {
  __shared__ __align__(16) short lds[16384];  // Ah[8k] Al Bh Bl frags of 512 shorts
  const int t = threadIdx.x;
  const int bx = blockIdx.x;
  const int zblk = bx >> 2, csp = bx & 3;
  const int wid = t >> 6, l = t & 63;
  const int wr = wid >> 1, wc = wid & 1;
  const int lg = l >> 4, lo16 = l & 15;
  const int rowbase = zblk * 128;

  const short* sarr = (wid == 0) ? Eh : (wid == 1) ? El : (wid == 2) ? Zh : Zl;
  const bool is_a = (wid < 2);
  const int base_off = lo16 * 1024 + lg * 8;
  short* ldsw = lds + wid * 4096;
  const int lofs = l * 8;

  float s1[4], s2[4];
  int i1[4], i2[4];
#pragma unroll
  for (int i = 0; i < 4; ++i) {
    s1[i] = FLT_BIG; s2[i] = FLT_BIG; i1[i] = 0x7fffffff; i2[i] = 0x7fffffff;
  }

  for (int mt = 0; mt < 8; ++mt) {
    const int m0 = csp * 1024 + mt * 128;
    const int srow0 = is_a ? m0 : rowbase;
    const short* sp0 = sarr + (size_t)srow0 * 1024 + base_off;

    f32x4 acc[4][4];
#pragma unroll
    for (int mi = 0; mi < 4; ++mi)
#pragma unroll
      for (int ni = 0; ni < 4; ++ni) acc[mi][ni] = (f32x4){0.f, 0.f, 0.f, 0.f};

    for (int k0 = 0; k0 < 1024; k0 += 32) {
      __syncthreads();
      const short* sp = sp0 + k0;
#pragma unroll
      for (int u = 0; u < 8; ++u) GLOAD_LDS16(sp + u * 16384, ldsw + u * 512);
      __syncthreads();

      bf16x8 bh[4], bl[4];
#pragma unroll
      for (int ni = 0; ni < 4; ++ni) {
        bh[ni] = *(const bf16x8*)(lds + 8192 + (wc * 4 + ni) * 512 + lofs);
        bl[ni] = *(const bf16x8*)(lds + 12288 + (wc * 4 + ni) * 512 + lofs);
      }
#pragma unroll
      for (int mi = 0; mi < 4; ++mi) {
        bf16x8 ah = *(const bf16x8*)(lds + (wr * 4 + mi) * 512 + lofs);
        bf16x8 al = *(const bf16x8*)(lds + 4096 + (wr * 4 + mi) * 512 + lofs);
#pragma unroll
        for (int ni = 0; ni < 4; ++ni) {
          f32x4 c = acc[mi][ni];
          c = __builtin_amdgcn_mfma_f32_16x16x32_bf16(ah, bh[ni], c, 0, 0, 0);
          c = __builtin_amdgcn_mfma_f32_16x16x32_bf16(ah, bl[ni], c, 0, 0, 0);
          c = __builtin_amdgcn_mfma_f32_16x16x32_bf16(al, bh[ni], c, 0, 0, 0);
          acc[mi][ni] = c;
        }
      }
    }
    // epilogue: scores + top-2 (per ni slot = one z-row per lane)
#pragma unroll
    for (int mi = 0; mi < 4; ++mi) {
      const int c0 = m0 + wr * 64 + mi * 16 + lg * 4;
      float4 es = *(const float4*)(e_sq + c0);
      float esv[4] = {es.x, es.y, es.z, es.w};
#pragma unroll
      for (int ni = 0; ni < 4; ++ni) {
#pragma unroll
        for (int j = 0; j < 4; ++j) {
          const float s = fmaf(-2.0f, acc[mi][ni][j], esv[j]);
          const int c = c0 + j;
          if (s < s1[ni]) {
            s2[ni] = s1[ni]; i2[ni] = i1[ni]; s1[ni] = s; i1[ni] = c;
          } else if (s < s2[ni]) {
            s2[ni] = s; i2[ni] = c;
          }
        }
      }
    }
  }

  __syncthreads();
  unsigned long long* red = (unsigned long long*)lds;
#pragma unroll
  for (int ni = 0; ni < 4; ++ni) {
    unsigned long long k1v =
        (((unsigned long long)fkey(s1[ni])) << 32) | (unsigned)i1[ni];
    unsigned long long k2v =
        (((unsigned long long)fkey(s2[ni])) << 32) | (unsigned)i2[ni];
    unsigned long long o1 = __shfl_xor(k1v, 16), o2 = __shfl_xor(k2v, 16);
    merge2(k1v, k2v, o1, o2);
    o1 = __shfl_xor(k1v, 32); o2 = __shfl_xor(k2v, 32);
    merge2(k1v, k2v, o1, o2);
    if (lg == 0) {
      const int r = wc * 64 + ni * 16 + lo16;
      red[(wr * 128 + r) * 2 + 0] = k1v;
      red[(wr * 128 + r) * 2 + 1] = k2v;
    }
  }
  __syncthreads();
  if (t < 128) {
    unsigned long long a1 = red[t * 2 + 0], a2 = red[t * 2 + 1];
    merge2(a1, a2, red[256 + t * 2 + 0], red[256 + t * 2 + 1]);
    unsigned long long* pp =
        part + ((size_t)csp * chunk + rowbase + t) * 2;
    pp[0] = a1; pp[1] = a2;
  }
}

// ---------------- K3: combine + near-tie exact full-rescan ----------------
__global__ __launch_bounds__(256) void k_rescore2(
    const float* __restrict__ x, const float* __restrict__ ln_g,
    const float* __restrict__ ln_b, const float* __restrict__ w_pre,
    const float* __restrict__ b_pre, const float* __restrict__ embed,
    const unsigned long long* __restrict__ part, const float* __restrict__ z_sq,
    int* __restrict__ idxf, float* __restrict__ crow,
    float* __restrict__ out_idx, int chunk, int row0) {
  __shared__ float gsh[256];
  __shared__ float zrow[1024];
  __shared__ double wd[4];
  __shared__ int wcidx[4];
  __shared__ double dfin;
  __shared__ int ifin;
  const int t = threadIdx.x;
  const int wid = t >> 6, l = t & 63;

  for (int rr = 0; rr < 64; ++rr) {
    const int lrow = blockIdx.x * 64 + rr;
    const int grow = row0 + lrow;
    unsigned long long b1 = part[((size_t)0 * chunk + lrow) * 2];
    unsigned long long b2 = part[((size_t)0 * chunk + lrow) * 2 + 1];
#pragma unroll
    for (int sp = 1; sp < 4; ++sp)
      merge2(b1, b2, part[((size_t)sp * chunk + lrow) * 2],
             part[((size_t)sp * chunk + lrow) * 2 + 1]);
    float s1 = keyinv((unsigned)(b1 >> 32));
    float s2 = keyinv((unsigned)(b2 >> 32));
    int fin = (int)(b1 & 0xFFFFFFFFull);
    float cval = z_sq[grow] + s1;

    if (s2 - s1 < MARGIN) {  // block-uniform condition
      // --- recompute z row bit-exactly as k1 ---
      if (t < 64) {
        float4 v = *(const float4*)(x + (size_t)grow * DIMX + t * 4);
        float s = v.x + v.y + v.z + v.w;
        float ss = v.x * v.x + v.y * v.y + v.z * v.z + v.w * v.w;
#pragma unroll
        for (int o = 32; o > 0; o >>= 1) { s += __shfl_xor(s, o); ss += __shfl_xor(ss, o); }
        const float mu = s * (1.0f / 256.0f);
        const float var = ss * (1.0f / 256.0f) - mu * mu;
        const float rstd = rsqrtf(var + 1e-5f);
        float vv[4] = {v.x, v.y, v.z, v.w};
#pragma unroll
        for (int q = 0; q < 4; ++q) {
          const int d = t * 4 + q;
          float xn = (vv[q] - mu) * rstd * ln_g[d] + ln_b[d];
          gsh[d] = 0.5f * xn * (1.0f + erff(xn * 0.70710678118654752f));
        }
      }
      __syncthreads();
      float a0 = 0.f, a1f = 0.f, a2f = 0.f, a3f = 0.f;
      for (int d = 0; d < DIMX; ++d) {
        float4 w = *(const float4*)(w_pre + (size_t)d * CDIM + t * 4);
        const float gv = gsh[d];
        a0 = fmaf(gv, w.x, a0); a1f = fmaf(gv, w.y, a1f);
        a2f = fmaf(gv, w.z, a2f); a3f = fmaf(gv, w.w, a3f);
      }
      float4 bp = *(const float4*)(b_pre + t * 4);
      zrow[t * 4 + 0] = a0 + bp.x; zrow[t * 4 + 1] = a1f + bp.y;
      zrow[t * 4 + 2] = a2f + bp.z; zrow[t * 4 + 3] = a3f + bp.w;
      __syncthreads();
      // --- exact f64 scan over all 4096 codes, waves split codes ---
      double dmin = 1e300; int cmin = 0x7fffffff;
      for (int ci = 0; ci < 1024; ++ci) {
        const int c = wid * 1024 + ci;
        const float* e = embed + (size_t)c * CDIM;
        double dd = 0.0;
#pragma unroll 4
        for (int j = 0; j < 16; ++j) {
          const int kk = l * 16 + j;
          const double df = (double)zrow[kk] - (double)e[kk];
          dd = fma(df, df, dd);
        }
#pragma unroll
        for (int o = 32; o > 0; o >>= 1) dd += __shfl_xor(dd, o);
        if (dd < dmin) { dmin = dd; cmin = c; }
      }
      if (l == 0) { wd[wid] = dmin; wcidx[wid] = cmin; }
      __syncthreads();
      if (t == 0) {
        double dm = wd[0]; int cm = wcidx[0];
#pragma unroll
        for (int wv = 1; wv < 4; ++wv) {
          if (wd[wv] < dm || (wd[wv] == dm && wcidx[wv] < cm)) {
            dm = wd[wv]; cm = wcidx[wv];
          }
        }
        dfin = dm; ifin = cm;
      }
      __syncthreads();
      fin = ifin;
      cval = (float)dfin;
      __syncthreads();
    }
    if (t == 0) {
      idxf[grow] = fin;
      out_idx[grow] = (float)fin;
      crow[grow] = cval;
    }
  }
}

// ---------------- K4: E_post = embed @ w_post ----------------
__global__ __launch_bounds__(256) void k_epost(const float* __restrict__ E,
                                               const float* __restrict__ w_post,
                                               float* __restrict__ E_post) {
  __shared__ float es[16][128];
  const int t = threadIdx.x;
  const int r0 = blockIdx.x * 16;
  float acc[16];
#pragma unroll
  for (int r = 0; r < 16; ++r) acc[r] = 0.f;
  for (int k0 = 0; k0 < CDIM; k0 += 128) {
    __syncthreads();
#pragma unroll
    for (int p = 0; p < 2; ++p) {
      const int fl = (p * 256 + t) * 4;
      const int r = fl >> 7, kk = fl & 127;
      float4 v = *(const float4*)(E + (size_t)(r0 + r) * CDIM + k0 + kk);
      *(float4*)&es[r][kk] = v;
    }
    __syncthreads();
#pragma unroll 4
    for (int d = 0; d < 128; ++d) {
      const float w = w_post[(size_t)(k0 + d) * DIMX + t];
#pragma unroll
      for (int r = 0; r < 16; ++r) acc[r] = fmaf(es[r][d], w, acc[r]);
    }
  }
#pragma unroll
  for (int r = 0; r < 16; ++r)
    E_post[(size_t)(r0 + r) * DIMX + t] = acc[r];
}

// ---------------- K5: gather E_post rows + bias ----------------
__global__ __launch_bounds__(256) void k_gather(const float* __restrict__ E_post,
                                                const int* __restrict__ idx,
                                                const float* __restrict__ b_post,
                                                float* __restrict__ outq) {
  const int t = threadIdx.x;
  const int r0 = blockIdx.x * 16;
  const float bp = b_post[t];
#pragma unroll
  for (int i = 0; i < 16; ++i) {
    const int row = r0 + i;
    outq[(size_t)row * DIMX + t] = E_post[(size_t)idx[row] * DIMX + t] + bp;
  }
}

// ---------------- K6: commit reduce ----------------
__global__ __launch_bounds__(256) void k_commit_final(
    const float* __restrict__ crow, float* __restrict__ out_commit) {
  const int t = threadIdx.x;
  double s = 0.0;
  for (int i = t; i < BN_ROWS; i += 256) s += (double)crow[i];
#pragma unroll
  for (int o = 32; o > 0; o >>= 1) s += __shfl_xor(s, o);
  __shared__ double wsum[4];
  if ((t & 63) == 0) wsum[t >> 6] = s;
  __syncthreads();
  if (t == 0)
    *out_commit = (float)(0.25 * (wsum[0] + wsum[1] + wsum[2] + wsum[3]) /
                          (65536.0 * 1024.0));
}

extern "C" void kernel_launch(void* const* d_in, const int* in_sizes, int n_in,
                              void* d_out, int out_size, void* d_ws,
                              size_t ws_size, hipStream_t stream) {
  const float* x = (const float*)d_in[0];
  const float* ln_g = (const float*)d_in[1];
  const float* ln_b = (const float*)d_in[2];
  const float* w_pre = (const float*)d_in[3];
  const float* b_pre = (const float*)d_in[4];
  const float* embed = (const float*)d_in[5];
  const float* w_post = (const float*)d_in[6];
  const float* b_post = (const float*)d_in[7];

  float* out = (float*)d_out;
  float* outq = out;                   // 16777216 f32
  float* out_idx = out + 16777216;     // 65536 f32
  float* out_commit = out + 16842752;  // 1 f32

  char* ws = (char*)d_ws;
  float* e_sq = (float*)(ws + OFF_ESQ);
  float* z_sq = (float*)(ws + OFF_ZSQ);
  int* idxf = (int*)(ws + OFF_IDXF);
  float* crow = (float*)(ws + OFF_CROW);
  float* E_post = (float*)(ws + OFF_EPOST);
  short* Eh = (short*)(ws + OFF_EH);
  short* El = (short*)(ws + OFF_EL);

  // chunk rows sized to ws: per-row = 64B (part) + 4KB (z hi/lo)
  int chunk = 4096;
  while (chunk < BN_ROWS &&
         OFF_PART + (size_t)(chunk * 2) * 4160ull <= ws_size)
    chunk *= 2;
  unsigned long long* part = (unsigned long long*)(ws + OFF_PART);
  short* zh = (short*)(ws + OFF_PART + (size_t)chunk * 64);
  short* zl = (short*)(ws + OFF_PART + (size_t)chunk * 64 + (size_t)chunk * 2048);

  k_esq<<<KCODES / 4, 256, 0, stream>>>(embed, e_sq);
  k_ehilo<<<KCODES, 256, 0, stream>>>(embed, Eh, El);
  k_epost<<<KCODES / 16, 256, 0, stream>>>(embed, w_post, E_post);

  for (int row0 = 0; row0 < BN_ROWS; row0 += chunk) {
    k_ln_gelu_gemm<<<chunk / 16, 256, 0, stream>>>(x, ln_g, ln_b, w_pre, b_pre,
                                                   zh, zl, z_sq, row0);
    k_score<<<(chunk / 128) * 4, 256, 0, stream>>>(Eh, El, zh, zl, e_sq, part,
                                                   chunk);
    k_rescore2<<<chunk / 64, 256, 0, stream>>>(x, ln_g, ln_b, w_pre, b_pre,
                                               embed, part, z_sq, idxf, crow,
                                               out_idx, chunk, row0);
  }

  k_gather<<<BN_ROWS / 16, 256, 0, stream>>>(E_post, idxf, b_post, outq);
  k_commit_final<<<1, 256, 0, stream>>>(crow, out_commit);
}

// Round 4
// 3718.195 us; speedup vs baseline: 2.9372x; 1.7738x over previous
//
#include <hip/hip_runtime.h>

#define BN_ROWS 65536
#define DIMX 256
#define CDIM 1024
#define KCODES 4096
#define MARGIN 0.03f
#define FLT_BIG 3.402823466e+38f

// ---------------- ws layout (bytes) ----------------
static const size_t OFF_ESQ   = 0;          // 4096 f32 (16KB)
static const size_t OFF_ZSQ   = 16384;      // 65536 f32
static const size_t OFF_IDXF  = 278528;     // 65536 i32
static const size_t OFF_CROW  = 540672;     // 65536 f32
static const size_t OFF_EPOST = 802816;     // 4096*256 f32 (4MB)
static const size_t OFF_EH    = 4997120;    // 4096*1024 bf16 (8MB)
static const size_t OFF_EL    = 13385728;   // 4096*1024 bf16 (8MB)
static const size_t OFF_NFLAG = 21774336;   // 1 i32 (+pad 64B)
static const size_t OFF_FLAG  = 21774400;   // 65536 i32 (256KB)
static const size_t OFF_PART  = 22036544;   // 4 * chunk * 16B
// zh = OFF_PART + chunk*64 ; zl = zh + chunk*2048

typedef __attribute__((ext_vector_type(8))) short bf16x8;
typedef __attribute__((ext_vector_type(4))) float f32x4;

#define GLOAD_LDS16(gsrc, ldst)                                                \
  __builtin_amdgcn_global_load_lds(                                            \
      (const __attribute__((address_space(1))) void*)(gsrc),                   \
      (__attribute__((address_space(3))) void*)(ldst), 16, 0, 0)

__device__ inline unsigned short bf_rtn(float f) {
  unsigned u = __float_as_uint(f);
  unsigned r = (u + 0x7FFFu + ((u >> 16) & 1u)) >> 16;
  return (unsigned short)r;
}
__device__ inline void bf_split(float f, unsigned short& h, unsigned short& l) {
  h = bf_rtn(f);
  float hf = __uint_as_float(((unsigned)h) << 16);
  l = bf_rtn(f - hf);
}
__device__ inline unsigned fkey(float s) {
  unsigned b = __float_as_uint(s);
  return b ^ ((unsigned)((int)b >> 31) | 0x80000000u);
}
__device__ inline float keyinv(unsigned k) {
  unsigned b = (k & 0x80000000u) ? (k ^ 0x80000000u) : ~k;
  return __uint_as_float(b);
}
__device__ inline void merge2(unsigned long long& a1, unsigned long long& a2,
                              unsigned long long b1, unsigned long long b2) {
  unsigned long long n1 = a1 < b1 ? a1 : b1;
  unsigned long long hi = a1 < b1 ? b1 : a1;
  unsigned long long m = a2 < b2 ? a2 : b2;
  a2 = hi < m ? hi : m;
  a1 = n1;
}

// ---------------- K0: e_sq ----------------
__global__ __launch_bounds__(256) void k_esq(const float* __restrict__ embed,
                                             float* __restrict__ e_sq) {
  const int t = threadIdx.x, wv = t >> 6, lane = t & 63;
  const int row = blockIdx.x * 4 + wv;
  const float* e = embed + (size_t)row * CDIM;
  float s = 0.f;
  for (int k = lane * 4; k < CDIM; k += 256) {
    float4 v = *(const float4*)(e + k);
    s = fmaf(v.x, v.x, s); s = fmaf(v.y, v.y, s);
    s = fmaf(v.z, v.z, s); s = fmaf(v.w, v.w, s);
  }
#pragma unroll
  for (int o = 32; o > 0; o >>= 1) s += __shfl_xor(s, o);
  if (lane == 0) e_sq[row] = s;
}

// ---------------- K0b: E -> hi/lo bf16 ----------------
__global__ __launch_bounds__(256) void k_ehilo(const float* __restrict__ embed,
                                               short* __restrict__ Eh,
                                               short* __restrict__ El) {
  const int t = threadIdx.x;
  const size_t row = blockIdx.x;
  float4 v = *(const float4*)(embed + row * CDIM + t * 4);
  unsigned short h0, l0, h1, l1, h2, l2, h3, l3;
  bf_split(v.x, h0, l0); bf_split(v.y, h1, l1);
  bf_split(v.z, h2, l2); bf_split(v.w, h3, l3);
  *(short4*)(Eh + row * CDIM + t * 4) =
      make_short4((short)h0, (short)h1, (short)h2, (short)h3);
  *(short4*)(El + row * CDIM + t * 4) =
      make_short4((short)l0, (short)l1, (short)l2, (short)l3);
}

// ---------------- K1: LN + GELU + @w_pre -> z hi/lo + z_sq ----------------
__global__ __launch_bounds__(256) void k_ln_gelu_gemm(
    const float* __restrict__ x, const float* __restrict__ ln_g,
    const float* __restrict__ ln_b, const float* __restrict__ w_pre,
    const float* __restrict__ b_pre, short* __restrict__ zh,
    short* __restrict__ zl, float* __restrict__ z_sq, int row0) {
  __shared__ float g[16][DIMX];
  const int t = threadIdx.x;
  const int lrow0 = blockIdx.x * 16;
  const int grow0 = row0 + lrow0;
  const int wv = t >> 6, lane = t & 63;
#pragma unroll
  for (int j = 0; j < 4; ++j) {
    const int r = wv * 4 + j;
    const float* xr = x + (size_t)(grow0 + r) * DIMX;
    float4 v = *(const float4*)(xr + lane * 4);
    float s = v.x + v.y + v.z + v.w;
    float ss = v.x * v.x + v.y * v.y + v.z * v.z + v.w * v.w;
#pragma unroll
    for (int o = 32; o > 0; o >>= 1) { s += __shfl_xor(s, o); ss += __shfl_xor(ss, o); }
    const float mu = s * (1.0f / 256.0f);
    const float var = ss * (1.0f / 256.0f) - mu * mu;
    const float rstd = rsqrtf(var + 1e-5f);
    float vv[4] = {v.x, v.y, v.z, v.w};
#pragma unroll
    for (int q = 0; q < 4; ++q) {
      const int d = lane * 4 + q;
      float xn = (vv[q] - mu) * rstd * ln_g[d] + ln_b[d];
      g[r][d] = 0.5f * xn * (1.0f + erff(xn * 0.70710678118654752f));
    }
  }
  __syncthreads();
  float acc[16][4];
#pragma unroll
  for (int r = 0; r < 16; ++r)
#pragma unroll
    for (int c = 0; c < 4; ++c) acc[r][c] = 0.f;
#pragma unroll 4
  for (int d = 0; d < DIMX; ++d) {
    float4 w = *(const float4*)(w_pre + (size_t)d * CDIM + t * 4);
#pragma unroll
    for (int r = 0; r < 16; ++r) {
      const float gv = g[r][d];
      acc[r][0] = fmaf(gv, w.x, acc[r][0]);
      acc[r][1] = fmaf(gv, w.y, acc[r][1]);
      acc[r][2] = fmaf(gv, w.z, acc[r][2]);
      acc[r][3] = fmaf(gv, w.w, acc[r][3]);
    }
  }
  float4 bp = *(const float4*)(b_pre + t * 4);
  float ps[16];
#pragma unroll
  for (int r = 0; r < 16; ++r) {
    float4 o;
    o.x = acc[r][0] + bp.x; o.y = acc[r][1] + bp.y;
    o.z = acc[r][2] + bp.z; o.w = acc[r][3] + bp.w;
    unsigned short h0, l0, h1, l1, h2, l2, h3, l3;
    bf_split(o.x, h0, l0); bf_split(o.y, h1, l1);
    bf_split(o.z, h2, l2); bf_split(o.w, h3, l3);
    *(short4*)(zh + (size_t)(lrow0 + r) * CDIM + t * 4) =
        make_short4((short)h0, (short)h1, (short)h2, (short)h3);
    *(short4*)(zl + (size_t)(lrow0 + r) * CDIM + t * 4) =
        make_short4((short)l0, (short)l1, (short)l2, (short)l3);
    ps[r] = o.x * o.x + o.y * o.y + o.z * o.z + o.w * o.w;
  }
#pragma unroll
  for (int r = 0; r < 16; ++r)
#pragma unroll
    for (int o = 32; o > 0; o >>= 1) ps[r] += __shfl_xor(ps[r], o);
  __shared__ float zps[4][16];
  if (lane == 0)
#pragma unroll
    for (int r = 0; r < 16; ++r) zps[wv][r] = ps[r];
  __syncthreads();
  if (t < 16) z_sq[grow0 + t] = zps[0][t] + zps[1][t] + zps[2][t] + zps[3][t];
}

// ---------------- K2: bf16x3 MFMA score GEMM + top-2 (per code-split) --------
__global__ __launch_bounds__(256, 2) void k_score(
    const short* __restrict__ Eh, const short* __restrict__ El,
    const short* __restrict__ Zh, const short* __restrict__ Zl,
    const float* __restrict__ e_sq, unsigned long long* __restrict__ part,
    int chunk) {
  __shared__ __align__(16) short lds[16384];
  const int t = threadIdx.x;
  const int bx = blockIdx.x;
  const int zblk = bx >> 2, csp = bx & 3;
  const int wid = t >> 6, l = t & 63;
  const int wr = wid >> 1, wc = wid & 1;
  const int lg = l >> 4, lo16 = l & 15;
  const int rowbase = zblk * 128;

  const short* sarr = (wid == 0) ? Eh : (wid == 1) ? El : (wid == 2) ? Zh : Zl;
  const bool is_a = (wid < 2);
  const int base_off = lo16 * 1024 + lg * 8;
  short* ldsw = lds + wid * 4096;
  const int lofs = l * 8;

  float s1[4], s2[4];
  int i1[4], i2[4];
#pragma unroll
  for (int i = 0; i < 4; ++i) {
    s1[i] = FLT_BIG; s2[i] = FLT_BIG; i1[i] = 0x7fffffff; i2[i] = 0x7fffffff;
  }

  for (int mt = 0; mt < 8; ++mt) {
    const int m0 = csp * 1024 + mt * 128;
    const int srow0 = is_a ? m0 : rowbase;
    const short* sp0 = sarr + (size_t)srow0 * 1024 + base_off;

    f32x4 acc[4][4];
#pragma unroll
    for (int mi = 0; mi < 4; ++mi)
#pragma unroll
      for (int ni = 0; ni < 4; ++ni) acc[mi][ni] = (f32x4){0.f, 0.f, 0.f, 0.f};

    for (int k0 = 0; k0 < 1024; k0 += 32) {
      __syncthreads();
      const short* sp = sp0 + k0;
#pragma unroll
      for (int u = 0; u < 8; ++u) GLOAD_LDS16(sp + u * 16384, ldsw + u * 512);
      __syncthreads();

      bf16x8 bh[4], bl[4];
#pragma unroll
      for (int ni = 0; ni < 4; ++ni) {
        bh[ni] = *(const bf16x8*)(lds + 8192 + (wc * 4 + ni) * 512 + lofs);
        bl[ni] = *(const bf16x8*)(lds + 12288 + (wc * 4 + ni) * 512 + lofs);
      }
#pragma unroll
      for (int mi = 0; mi < 4; ++mi) {
        bf16x8 ah = *(const bf16x8*)(lds + (wr * 4 + mi) * 512 + lofs);
        bf16x8 al = *(const bf16x8*)(lds + 4096 + (wr * 4 + mi) * 512 + lofs);
#pragma unroll
        for (int ni = 0; ni < 4; ++ni) {
          f32x4 c = acc[mi][ni];
          c = __builtin_amdgcn_mfma_f32_16x16x32_bf16(ah, bh[ni], c, 0, 0, 0);
          c = __builtin_amdgcn_mfma_f32_16x16x32_bf16(ah, bl[ni], c, 0, 0, 0);
          c = __builtin_amdgcn_mfma_f32_16x16x32_bf16(al, bh[ni], c, 0, 0, 0);
          acc[mi][ni] = c;
        }
      }
    }
#pragma unroll
    for (int mi = 0; mi < 4; ++mi) {
      const int c0 = m0 + wr * 64 + mi * 16 + lg * 4;
      float4 es = *(const float4*)(e_sq + c0);
      float esv[4] = {es.x, es.y, es.z, es.w};
#pragma unroll
      for (int ni = 0; ni < 4; ++ni) {
#pragma unroll
        for (int j = 0; j < 4; ++j) {
          const float s = fmaf(-2.0f, acc[mi][ni][j], esv[j]);
          const int c = c0 + j;
          if (s < s1[ni]) {
            s2[ni] = s1[ni]; i2[ni] = i1[ni]; s1[ni] = s; i1[ni] = c;
          } else if (s < s2[ni]) {
            s2[ni] = s; i2[ni] = c;
          }
        }
      }
    }
  }

  __syncthreads();
  unsigned long long* red = (unsigned long long*)lds;
#pragma unroll
  for (int ni = 0; ni < 4; ++ni) {
    unsigned long long k1v =
        (((unsigned long long)fkey(s1[ni])) << 32) | (unsigned)i1[ni];
    unsigned long long k2v =
        (((unsigned long long)fkey(s2[ni])) << 32) | (unsigned)i2[ni];
    unsigned long long o1 = __shfl_xor(k1v, 16), o2 = __shfl_xor(k2v, 16);
    merge2(k1v, k2v, o1, o2);
    o1 = __shfl_xor(k1v, 32); o2 = __shfl_xor(k2v, 32);
    merge2(k1v, k2v, o1, o2);
    if (lg == 0) {
      const int r = wc * 64 + ni * 16 + lo16;
      red[(wr * 128 + r) * 2 + 0] = k1v;
      red[(wr * 128 + r) * 2 + 1] = k2v;
    }
  }
  __syncthreads();
  if (t < 128) {
    unsigned long long a1 = red[t * 2 + 0], a2 = red[t * 2 + 1];
    merge2(a1, a2, red[256 + t * 2 + 0], red[256 + t * 2 + 1]);
    unsigned long long* pp = part + ((size_t)csp * chunk + rowbase + t) * 2;
    pp[0] = a1; pp[1] = a2;
  }
}

// ---------------- K3a: combine partials, flag near-ties ----------------
__global__ __launch_bounds__(256) void k_combine(
    const unsigned long long* __restrict__ part, const float* __restrict__ z_sq,
    int* __restrict__ idxf, float* __restrict__ crow,
    float* __restrict__ out_idx, int* __restrict__ flag_rows,
    int* __restrict__ nflag, int chunk, int row0) {
  const int lrow = blockIdx.x * 256 + threadIdx.x;
  if (lrow >= chunk) return;
  const int grow = row0 + lrow;
  unsigned long long b1 = part[(size_t)lrow * 2];
  unsigned long long b2 = part[(size_t)lrow * 2 + 1];
#pragma unroll
  for (int sp = 1; sp < 4; ++sp)
    merge2(b1, b2, part[((size_t)sp * chunk + lrow) * 2],
           part[((size_t)sp * chunk + lrow) * 2 + 1]);
  const float s1 = keyinv((unsigned)(b1 >> 32));
  const float s2 = keyinv((unsigned)(b2 >> 32));
  const int fin = (int)(b1 & 0xFFFFFFFFull);
  idxf[grow] = fin;
  out_idx[grow] = (float)fin;
  crow[grow] = z_sq[grow] + s1;
  if (s2 - s1 < MARGIN) {
    const int slot = atomicAdd(nflag, 1);
    flag_rows[slot] = grow;
  }
}

// ---------------- K3b: exact f64 full rescan of flagged rows ----------------
__global__ __launch_bounds__(256) void k_exact(
    const float* __restrict__ x, const float* __restrict__ ln_g,
    const float* __restrict__ ln_b, const float* __restrict__ w_pre,
    const float* __restrict__ b_pre, const float* __restrict__ embed,
    const int* __restrict__ flag_rows, const int* __restrict__ nflag,
    int* __restrict__ idxf, float* __restrict__ crow,
    float* __restrict__ out_idx) {
  __shared__ float gsh[256];
  __shared__ float zrow[1024];
  __shared__ double wd[4];
  __shared__ int wcidx[4];
  const int t = threadIdx.x;
  const int wid = t >> 6, l = t & 63;
  const int n = *nflag;

  for (int fi = blockIdx.x; fi < n; fi += gridDim.x) {
    const int grow = flag_rows[fi];
    // recompute z row bit-exactly as k1
    if (t < 64) {
      float4 v = *(const float4*)(x + (size_t)grow * DIMX + t * 4);
      float s = v.x + v.y + v.z + v.w;
      float ss = v.x * v.x + v.y * v.y + v.z * v.z + v.w * v.w;
#pragma unroll
      for (int o = 32; o > 0; o >>= 1) { s += __shfl_xor(s, o); ss += __shfl_xor(ss, o); }
      const float mu = s * (1.0f / 256.0f);
      const float var = ss * (1.0f / 256.0f) - mu * mu;
      const float rstd = rsqrtf(var + 1e-5f);
      float vv[4] = {v.x, v.y, v.z, v.w};
#pragma unroll
      for (int q = 0; q < 4; ++q) {
        const int d = t * 4 + q;
        float xn = (vv[q] - mu) * rstd * ln_g[d] + ln_b[d];
        gsh[d] = 0.5f * xn * (1.0f + erff(xn * 0.70710678118654752f));
      }
    }
    __syncthreads();
    float a0 = 0.f, a1f = 0.f, a2f = 0.f, a3f = 0.f;
    for (int d = 0; d < DIMX; ++d) {
      float4 w = *(const float4*)(w_pre + (size_t)d * CDIM + t * 4);
      const float gv = gsh[d];
      a0 = fmaf(gv, w.x, a0); a1f = fmaf(gv, w.y, a1f);
      a2f = fmaf(gv, w.z, a2f); a3f = fmaf(gv, w.w, a3f);
    }
    float4 bp = *(const float4*)(b_pre + t * 4);
    zrow[t * 4 + 0] = a0 + bp.x; zrow[t * 4 + 1] = a1f + bp.y;
    zrow[t * 4 + 2] = a2f + bp.z; zrow[t * 4 + 3] = a3f + bp.w;
    __syncthreads();
    // lane-major: lane l owns elements l + 64*j (conflict-free)
    float zr[16];
#pragma unroll
    for (int j = 0; j < 16; ++j) zr[j] = zrow[l + 64 * j];
    double dmin = 1e300;
    int cmin = 0x7fffffff;
    for (int ci = 0; ci < 1024; ++ci) {
      const int c = wid * 1024 + ci;
      const float* e = embed + (size_t)c * CDIM;
      double dd = 0.0;
#pragma unroll
      for (int j = 0; j < 16; ++j) {
        const double df = (double)zr[j] - (double)e[l + 64 * j];
        dd = fma(df, df, dd);
      }
#pragma unroll
      for (int o = 32; o > 0; o >>= 1) dd += __shfl_xor(dd, o);
      if (dd < dmin) { dmin = dd; cmin = c; }
    }
    if (l == 0) { wd[wid] = dmin; wcidx[wid] = cmin; }
    __syncthreads();
    if (t == 0) {
      double dm = wd[0]; int cm = wcidx[0];
#pragma unroll
      for (int wv = 1; wv < 4; ++wv) {
        if (wd[wv] < dm || (wd[wv] == dm && wcidx[wv] < cm)) {
          dm = wd[wv]; cm = wcidx[wv];
        }
      }
      idxf[grow] = cm;
      out_idx[grow] = (float)cm;
      crow[grow] = (float)dm;
    }
    __syncthreads();
  }
}

// ---------------- K4: E_post = embed @ w_post ----------------
__global__ __launch_bounds__(256) void k_epost(const float* __restrict__ E,
                                               const float* __restrict__ w_post,
                                               float* __restrict__ E_post) {
  __shared__ float es[16][128];
  const int t = threadIdx.x;
  const int r0 = blockIdx.x * 16;
  float acc[16];
#pragma unroll
  for (int r = 0; r < 16; ++r) acc[r] = 0.f;
  for (int k0 = 0; k0 < CDIM; k0 += 128) {
    __syncthreads();
#pragma unroll
    for (int p = 0; p < 2; ++p) {
      const int fl = (p * 256 + t) * 4;
      const int r = fl >> 7, kk = fl & 127;
      float4 v = *(const float4*)(E + (size_t)(r0 + r) * CDIM + k0 + kk);
      *(float4*)&es[r][kk] = v;
    }
    __syncthreads();
#pragma unroll 4
    for (int d = 0; d < 128; ++d) {
      const float w = w_post[(size_t)(k0 + d) * DIMX + t];
#pragma unroll
      for (int r = 0; r < 16; ++r) acc[r] = fmaf(es[r][d], w, acc[r]);
    }
  }
#pragma unroll
  for (int r = 0; r < 16; ++r)
    E_post[(size_t)(r0 + r) * DIMX + t] = acc[r];
}

// ---------------- K5: gather E_post rows + bias ----------------
__global__ __launch_bounds__(256) void k_gather(const float* __restrict__ E_post,
                                                const int* __restrict__ idx,
                                                const float* __restrict__ b_post,
                                                float* __restrict__ outq) {
  const int t = threadIdx.x;
  const int r0 = blockIdx.x * 16;
  const float bp = b_post[t];
#pragma unroll
  for (int i = 0; i < 16; ++i) {
    const int row = r0 + i;
    outq[(size_t)row * DIMX + t] = E_post[(size_t)idx[row] * DIMX + t] + bp;
  }
}

// ---------------- K6: commit reduce ----------------
__global__ __launch_bounds__(256) void k_commit_final(
    const float* __restrict__ crow, float* __restrict__ out_commit) {
  const int t = threadIdx.x;
  double s = 0.0;
  for (int i = t; i < BN_ROWS; i += 256) s += (double)crow[i];
#pragma unroll
  for (int o = 32; o > 0; o >>= 1) s += __shfl_xor(s, o);
  __shared__ double wsum[4];
  if ((t & 63) == 0) wsum[t >> 6] = s;
  __syncthreads();
  if (t == 0)
    *out_commit = (float)(0.25 * (wsum[0] + wsum[1] + wsum[2] + wsum[3]) /
                          (65536.0 * 1024.0));
}

extern "C" void kernel_launch(void* const* d_in, const int* in_sizes, int n_in,
                              void* d_out, int out_size, void* d_ws,
                              size_t ws_size, hipStream_t stream) {
  const float* x = (const float*)d_in[0];
  const float* ln_g = (const float*)d_in[1];
  const float* ln_b = (const float*)d_in[2];
  const float* w_pre = (const float*)d_in[3];
  const float* b_pre = (const float*)d_in[4];
  const float* embed = (const float*)d_in[5];
  const float* w_post = (const float*)d_in[6];
  const float* b_post = (const float*)d_in[7];

  float* out = (float*)d_out;
  float* outq = out;                   // 16777216 f32
  float* out_idx = out + 16777216;     // 65536 f32
  float* out_commit = out + 16842752;  // 1 f32

  char* ws = (char*)d_ws;
  float* e_sq = (float*)(ws + OFF_ESQ);
  float* z_sq = (float*)(ws + OFF_ZSQ);
  int* idxf = (int*)(ws + OFF_IDXF);
  float* crow = (float*)(ws + OFF_CROW);
  float* E_post = (float*)(ws + OFF_EPOST);
  short* Eh = (short*)(ws + OFF_EH);
  short* El = (short*)(ws + OFF_EL);
  int* nflag = (int*)(ws + OFF_NFLAG);
  int* flag_rows = (int*)(ws + OFF_FLAG);

  // chunk rows sized to ws: per-row = 64B (part) + 4096B (zh+zl)
  int chunk = 4096;
  while (chunk < BN_ROWS &&
         OFF_PART + (size_t)(chunk * 2) * 4160ull <= ws_size)
    chunk *= 2;
  unsigned long long* part = (unsigned long long*)(ws + OFF_PART);
  short* zh = (short*)(ws + OFF_PART + (size_t)chunk * 64);
  short* zl = (short*)(ws + OFF_PART + (size_t)chunk * 64 + (size_t)chunk * 2048);

  hipMemsetAsync(nflag, 0, sizeof(int), stream);
  k_esq<<<KCODES / 4, 256, 0, stream>>>(embed, e_sq);
  k_ehilo<<<KCODES, 256, 0, stream>>>(embed, Eh, El);
  k_epost<<<KCODES / 16, 256, 0, stream>>>(embed, w_post, E_post);

  for (int row0 = 0; row0 < BN_ROWS; row0 += chunk) {
    k_ln_gelu_gemm<<<chunk / 16, 256, 0, stream>>>(x, ln_g, ln_b, w_pre, b_pre,
                                                   zh, zl, z_sq, row0);
    k_score<<<(chunk / 128) * 4, 256, 0, stream>>>(Eh, El, zh, zl, e_sq, part,
                                                   chunk);
    k_combine<<<chunk / 256, 256, 0, stream>>>(part, z_sq, idxf, crow, out_idx,
                                               flag_rows, nflag, chunk, row0);
  }

  k_exact<<<1024, 256, 0, stream>>>(x, ln_g, ln_b, w_pre, b_pre, embed,
                                    flag_rows, nflag, idxf, crow, out_idx);
  k_gather<<<BN_ROWS / 16, 256, 0, stream>>>(E_post, idxf, b_post, outq);
  k_commit_final<<<1, 256, 0, stream>>>(crow, out_commit);
}

// Round 5
// 3595.904 us; speedup vs baseline: 3.0371x; 1.0340x over previous
//
#include <hip/hip_runtime.h>

#define BN_ROWS 65536
#define DIMX 256
#define CDIM 1024
#define KCODES 4096
#define MARGIN 0.03f
#define FLT_BIG 3.402823466e+38f

// ---------------- ws layout (bytes) ----------------
static const size_t OFF_ESQ   = 0;          // 4096 f32 (16KB)
static const size_t OFF_ZSQ   = 16384;      // 65536 f32
static const size_t OFF_IDXF  = 278528;     // 65536 i32
static const size_t OFF_CROW  = 540672;     // 65536 f32
static const size_t OFF_EPOST = 802816;     // 4096*256 f32 (4MB)
static const size_t OFF_EH    = 4997120;    // 4096*1024 bf16 (8MB)
static const size_t OFF_EL    = 13385728;   // 4096*1024 bf16 (8MB)
static const size_t OFF_NFLAG = 21774336;   // 1 i32 (+pad 64B)
static const size_t OFF_FLAG  = 21774400;   // 65536 i32 (256KB)
static const size_t OFF_PART  = 22036544;   // 32 * chunk * 16B
// zh = OFF_PART + chunk*512 ; zl = zh + chunk*2048

typedef __attribute__((ext_vector_type(8))) short bf16x8;
typedef __attribute__((ext_vector_type(4))) float f32x4;

#define GLOAD_LDS16(gsrc, ldst)                                                \
  __builtin_amdgcn_global_load_lds(                                            \
      (const __attribute__((address_space(1))) void*)(gsrc),                   \
      (__attribute__((address_space(3))) void*)(ldst), 16, 0, 0)

__device__ inline unsigned short bf_rtn(float f) {
  unsigned u = __float_as_uint(f);
  unsigned r = (u + 0x7FFFu + ((u >> 16) & 1u)) >> 16;
  return (unsigned short)r;
}
__device__ inline void bf_split(float f, unsigned short& h, unsigned short& l) {
  h = bf_rtn(f);
  float hf = __uint_as_float(((unsigned)h) << 16);
  l = bf_rtn(f - hf);
}
__device__ inline unsigned fkey(float s) {
  unsigned b = __float_as_uint(s);
  return b ^ ((unsigned)((int)b >> 31) | 0x80000000u);
}
__device__ inline float keyinv(unsigned k) {
  unsigned b = (k & 0x80000000u) ? (k ^ 0x80000000u) : ~k;
  return __uint_as_float(b);
}
__device__ inline void merge2(unsigned long long& a1, unsigned long long& a2,
                              unsigned long long b1, unsigned long long b2) {
  unsigned long long n1 = a1 < b1 ? a1 : b1;
  unsigned long long hi = a1 < b1 ? b1 : a1;
  unsigned long long m = a2 < b2 ? a2 : b2;
  a2 = hi < m ? hi : m;
  a1 = n1;
}

// ---------------- K0: e_sq ----------------
__global__ __launch_bounds__(256) void k_esq(const float* __restrict__ embed,
                                             float* __restrict__ e_sq) {
  const int t = threadIdx.x, wv = t >> 6, lane = t & 63;
  const int row = blockIdx.x * 4 + wv;
  const float* e = embed + (size_t)row * CDIM;
  float s = 0.f;
  for (int k = lane * 4; k < CDIM; k += 256) {
    float4 v = *(const float4*)(e + k);
    s = fmaf(v.x, v.x, s); s = fmaf(v.y, v.y, s);
    s = fmaf(v.z, v.z, s); s = fmaf(v.w, v.w, s);
  }
#pragma unroll
  for (int o = 32; o > 0; o >>= 1) s += __shfl_xor(s, o);
  if (lane == 0) e_sq[row] = s;
}

// ---------------- K0b: E -> hi/lo bf16 ----------------
__global__ __launch_bounds__(256) void k_ehilo(const float* __restrict__ embed,
                                               short* __restrict__ Eh,
                                               short* __restrict__ El) {
  const int t = threadIdx.x;
  const size_t row = blockIdx.x;
  float4 v = *(const float4*)(embed + row * CDIM + t * 4);
  unsigned short h0, l0, h1, l1, h2, l2, h3, l3;
  bf_split(v.x, h0, l0); bf_split(v.y, h1, l1);
  bf_split(v.z, h2, l2); bf_split(v.w, h3, l3);
  *(short4*)(Eh + row * CDIM + t * 4) =
      make_short4((short)h0, (short)h1, (short)h2, (short)h3);
  *(short4*)(El + row * CDIM + t * 4) =
      make_short4((short)l0, (short)l1, (short)l2, (short)l3);
}

// ---------------- K1: LN + GELU + @w_pre -> z hi/lo + z_sq ----------------
__global__ __launch_bounds__(256) void k_ln_gelu_gemm(
    const float* __restrict__ x, const float* __restrict__ ln_g,
    const float* __restrict__ ln_b, const float* __restrict__ w_pre,
    const float* __restrict__ b_pre, short* __restrict__ zh,
    short* __restrict__ zl, float* __restrict__ z_sq, int row0) {
  __shared__ float g[16][DIMX];
  const int t = threadIdx.x;
  const int lrow0 = blockIdx.x * 16;
  const int grow0 = row0 + lrow0;
  const int wv = t >> 6, lane = t & 63;
#pragma unroll
  for (int j = 0; j < 4; ++j) {
    const int r = wv * 4 + j;
    const float* xr = x + (size_t)(grow0 + r) * DIMX;
    float4 v = *(const float4*)(xr + lane * 4);
    float s = v.x + v.y + v.z + v.w;
    float ss = v.x * v.x + v.y * v.y + v.z * v.z + v.w * v.w;
#pragma unroll
    for (int o = 32; o > 0; o >>= 1) { s += __shfl_xor(s, o); ss += __shfl_xor(ss, o); }
    const float mu = s * (1.0f / 256.0f);
    const float var = ss * (1.0f / 256.0f) - mu * mu;
    const float rstd = rsqrtf(var + 1e-5f);
    float vv[4] = {v.x, v.y, v.z, v.w};
#pragma unroll
    for (int q = 0; q < 4; ++q) {
      const int d = lane * 4 + q;
      float xn = (vv[q] - mu) * rstd * ln_g[d] + ln_b[d];
      g[r][d] = 0.5f * xn * (1.0f + erff(xn * 0.70710678118654752f));
    }
  }
  __syncthreads();
  float acc[16][4];
#pragma unroll
  for (int r = 0; r < 16; ++r)
#pragma unroll
    for (int c = 0; c < 4; ++c) acc[r][c] = 0.f;
#pragma unroll 4
  for (int d = 0; d < DIMX; ++d) {
    float4 w = *(const float4*)(w_pre + (size_t)d * CDIM + t * 4);
#pragma unroll
    for (int r = 0; r < 16; ++r) {
      const float gv = g[r][d];
      acc[r][0] = fmaf(gv, w.x, acc[r][0]);
      acc[r][1] = fmaf(gv, w.y, acc[r][1]);
      acc[r][2] = fmaf(gv, w.z, acc[r][2]);
      acc[r][3] = fmaf(gv, w.w, acc[r][3]);
    }
  }
  float4 bp = *(const float4*)(b_pre + t * 4);
  float ps[16];
#pragma unroll
  for (int r = 0; r < 16; ++r) {
    float4 o;
    o.x = acc[r][0] + bp.x; o.y = acc[r][1] + bp.y;
    o.z = acc[r][2] + bp.z; o.w = acc[r][3] + bp.w;
    unsigned short h0, l0, h1, l1, h2, l2, h3, l3;
    bf_split(o.x, h0, l0); bf_split(o.y, h1, l1);
    bf_split(o.z, h2, l2); bf_split(o.w, h3, l3);
    *(short4*)(zh + (size_t)(lrow0 + r) * CDIM + t * 4) =
        make_short4((short)h0, (short)h1, (short)h2, (short)h3);
    *(short4*)(zl + (size_t)(lrow0 + r) * CDIM + t * 4) =
        make_short4((short)l0, (short)l1, (short)l2, (short)l3);
    ps[r] = o.x * o.x + o.y * o.y + o.z * o.z + o.w * o.w;
  }
#pragma unroll
  for (int r = 0; r < 16; ++r)
#pragma unroll
    for (int o = 32; o > 0; o >>= 1) ps[r] += __shfl_xor(ps[r], o);
  __shared__ float zps[4][16];
  if (lane == 0)
#pragma unroll
    for (int r = 0; r < 16; ++r) zps[wv][r] = ps[r];
  __syncthreads();
  if (t < 16) z_sq[grow0 + t] = zps[0][t] + zps[1][t] + zps[2][t] + zps[3][t];
}

// ---------------- K2: bf16x3 MFMA score GEMM + top-2 ----------------
// grid = (chunk/128)*32 blocks; block = 256 (4 waves, 2x2 wave tile)
// each block: 128 z-rows x 128 codes, full K=1024, 2-phase dbuf LDS
__global__ __launch_bounds__(256, 2) void k_score(
    const short* __restrict__ Eh, const short* __restrict__ El,
    const short* __restrict__ Zh, const short* __restrict__ Zl,
    const float* __restrict__ e_sq, unsigned long long* __restrict__ part,
    int chunk) {
  __shared__ __align__(16) short lds[2][16384];  // 64KB double-buffered
  const int t = threadIdx.x;
  // bijective XCD swizzle (gridDim.x % 8 == 0 always)
  const int cpx = gridDim.x >> 3;
  const int bx = (blockIdx.x & 7) * cpx + (blockIdx.x >> 3);
  const int zblk = bx >> 5, csp = bx & 31;
  const int wid = t >> 6, l = t & 63;
  const int wr = wid >> 1, wc = wid & 1;
  const int lg = l >> 4, lo16 = l & 15;
  const int rowbase = zblk * 128;
  const int m0 = csp * 128;

  const short* sarr = (wid == 0) ? Eh : (wid == 1) ? El : (wid == 2) ? Zh : Zl;
  const bool is_a = (wid < 2);
  const int srow0 = is_a ? m0 : rowbase;
  const short* sp0 = sarr + (size_t)srow0 * 1024 + lo16 * 1024 + lg * 8;
  short* ldsw0 = &lds[0][wid * 4096];
  short* ldsw1 = &lds[1][wid * 4096];
  const int lofs = l * 8;

  f32x4 acc[4][4];
#pragma unroll
  for (int mi = 0; mi < 4; ++mi)
#pragma unroll
    for (int ni = 0; ni < 4; ++ni) acc[mi][ni] = (f32x4){0.f, 0.f, 0.f, 0.f};

  // prologue: stage k0=0 into buf 0
#pragma unroll
  for (int u = 0; u < 8; ++u) GLOAD_LDS16(sp0 + u * 16384, ldsw0 + u * 512);
  __syncthreads();

  int cur = 0;
  for (int k0 = 0; k0 < 1024; k0 += 32) {
    // prefetch next k-step into the other buffer
    if (k0 + 32 < 1024) {
      const short* sp = sp0 + k0 + 32;
      short* dst = cur ? ldsw0 : ldsw1;
#pragma unroll
      for (int u = 0; u < 8; ++u) GLOAD_LDS16(sp + u * 16384, dst + u * 512);
    }
    const short* L = lds[cur];
    bf16x8 bh[4], bl[4];
#pragma unroll
    for (int ni = 0; ni < 4; ++ni) {
      bh[ni] = *(const bf16x8*)(L + 8192 + (wc * 4 + ni) * 512 + lofs);
      bl[ni] = *(const bf16x8*)(L + 12288 + (wc * 4 + ni) * 512 + lofs);
    }
#pragma unroll
    for (int mi = 0; mi < 4; ++mi) {
      bf16x8 ah = *(const bf16x8*)(L + (wr * 4 + mi) * 512 + lofs);
      bf16x8 al = *(const bf16x8*)(L + 4096 + (wr * 4 + mi) * 512 + lofs);
#pragma unroll
      for (int ni = 0; ni < 4; ++ni) {
        f32x4 c = acc[mi][ni];
        c = __builtin_amdgcn_mfma_f32_16x16x32_bf16(ah, bh[ni], c, 0, 0, 0);
        c = __builtin_amdgcn_mfma_f32_16x16x32_bf16(ah, bl[ni], c, 0, 0, 0);
        c = __builtin_amdgcn_mfma_f32_16x16x32_bf16(al, bh[ni], c, 0, 0, 0);
        acc[mi][ni] = c;
      }
    }
    __syncthreads();  // drains this iter's prefetch (vmcnt) + ds reads
    cur ^= 1;
  }

  // epilogue: scores + top-2 over this block's 128 codes
  float s1[4], s2[4];
  int i1[4], i2[4];
#pragma unroll
  for (int i = 0; i < 4; ++i) {
    s1[i] = FLT_BIG; s2[i] = FLT_BIG; i1[i] = 0x7fffffff; i2[i] = 0x7fffffff;
  }
#pragma unroll
  for (int mi = 0; mi < 4; ++mi) {
    const int c0 = m0 + wr * 64 + mi * 16 + lg * 4;
    float4 es = *(const float4*)(e_sq + c0);
    float esv[4] = {es.x, es.y, es.z, es.w};
#pragma unroll
    for (int ni = 0; ni < 4; ++ni) {
#pragma unroll
      for (int j = 0; j < 4; ++j) {
        const float s = fmaf(-2.0f, acc[mi][ni][j], esv[j]);
        const int c = c0 + j;
        if (s < s1[ni]) {
          s2[ni] = s1[ni]; i2[ni] = i1[ni]; s1[ni] = s; i1[ni] = c;
        } else if (s < s2[ni]) {
          s2[ni] = s; i2[ni] = c;
        }
      }
    }
  }

  unsigned long long* red = (unsigned long long*)lds;
#pragma unroll
  for (int ni = 0; ni < 4; ++ni) {
    unsigned long long k1v =
        (((unsigned long long)fkey(s1[ni])) << 32) | (unsigned)i1[ni];
    unsigned long long k2v =
        (((unsigned long long)fkey(s2[ni])) << 32) | (unsigned)i2[ni];
    unsigned long long o1 = __shfl_xor(k1v, 16), o2 = __shfl_xor(k2v, 16);
    merge2(k1v, k2v, o1, o2);
    o1 = __shfl_xor(k1v, 32); o2 = __shfl_xor(k2v, 32);
    merge2(k1v, k2v, o1, o2);
    if (lg == 0) {
      const int r = wc * 64 + ni * 16 + lo16;
      red[(wr * 128 + r) * 2 + 0] = k1v;
      red[(wr * 128 + r) * 2 + 1] = k2v;
    }
  }
  __syncthreads();
  if (t < 128) {
    unsigned long long a1 = red[t * 2 + 0], a2 = red[t * 2 + 1];
    merge2(a1, a2, red[256 + t * 2 + 0], red[256 + t * 2 + 1]);
    unsigned long long* pp = part + ((size_t)csp * chunk + rowbase + t) * 2;
    pp[0] = a1; pp[1] = a2;
  }
}

// ---------------- K3a: combine partials, flag near-ties ----------------
__global__ __launch_bounds__(256) void k_combine(
    const unsigned long long* __restrict__ part, const float* __restrict__ z_sq,
    int* __restrict__ idxf, float* __restrict__ crow,
    float* __restrict__ out_idx, int* __restrict__ flag_rows,
    int* __restrict__ nflag, int chunk, int row0) {
  const int lrow = blockIdx.x * 256 + threadIdx.x;
  if (lrow >= chunk) return;
  const int grow = row0 + lrow;
  unsigned long long b1 = part[(size_t)lrow * 2];
  unsigned long long b2 = part[(size_t)lrow * 2 + 1];
#pragma unroll
  for (int sp = 1; sp < 32; ++sp)
    merge2(b1, b2, part[((size_t)sp * chunk + lrow) * 2],
           part[((size_t)sp * chunk + lrow) * 2 + 1]);
  const float s1 = keyinv((unsigned)(b1 >> 32));
  const float s2 = keyinv((unsigned)(b2 >> 32));
  const int fin = (int)(b1 & 0xFFFFFFFFull);
  idxf[grow] = fin;
  out_idx[grow] = (float)fin;
  crow[grow] = z_sq[grow] + s1;
  if (s2 - s1 < MARGIN) {
    const int slot = atomicAdd(nflag, 1);
    flag_rows[slot] = grow;
  }
}

// ---------------- K3b: exact f64 full rescan of flagged rows ----------------
__global__ __launch_bounds__(256) void k_exact(
    const float* __restrict__ x, const float* __restrict__ ln_g,
    const float* __restrict__ ln_b, const float* __restrict__ w_pre,
    const float* __restrict__ b_pre, const float* __restrict__ embed,
    const int* __restrict__ flag_rows, const int* __restrict__ nflag,
    int* __restrict__ idxf, float* __restrict__ crow,
    float* __restrict__ out_idx) {
  __shared__ float gsh[256];
  __shared__ float zrow[1024];
  __shared__ double wd[4];
  __shared__ int wcidx[4];
  const int t = threadIdx.x;
  const int wid = t >> 6, l = t & 63;
  const int n = *nflag;

  for (int fi = blockIdx.x; fi < n; fi += gridDim.x) {
    const int grow = flag_rows[fi];
    if (t < 64) {
      float4 v = *(const float4*)(x + (size_t)grow * DIMX + t * 4);
      float s = v.x + v.y + v.z + v.w;
      float ss = v.x * v.x + v.y * v.y + v.z * v.z + v.w * v.w;
#pragma unroll
      for (int o = 32; o > 0; o >>= 1) { s += __shfl_xor(s, o); ss += __shfl_xor(ss, o); }
      const float mu = s * (1.0f / 256.0f);
      const float var = ss * (1.0f / 256.0f) - mu * mu;
      const float rstd = rsqrtf(var + 1e-5f);
      float vv[4] = {v.x, v.y, v.z, v.w};
#pragma unroll
      for (int q = 0; q < 4; ++q) {
        const int d = t * 4 + q;
        float xn = (vv[q] - mu) * rstd * ln_g[d] + ln_b[d];
        gsh[d] = 0.5f * xn * (1.0f + erff(xn * 0.70710678118654752f));
      }
    }
    __syncthreads();
    float a0 = 0.f, a1f = 0.f, a2f = 0.f, a3f = 0.f;
    for (int d = 0; d < DIMX; ++d) {
      float4 w = *(const float4*)(w_pre + (size_t)d * CDIM + t * 4);
      const float gv = gsh[d];
      a0 = fmaf(gv, w.x, a0); a1f = fmaf(gv, w.y, a1f);
      a2f = fmaf(gv, w.z, a2f); a3f = fmaf(gv, w.w, a3f);
    }
    float4 bp = *(const float4*)(b_pre + t * 4);
    zrow[t * 4 + 0] = a0 + bp.x; zrow[t * 4 + 1] = a1f + bp.y;
    zrow[t * 4 + 2] = a2f + bp.z; zrow[t * 4 + 3] = a3f + bp.w;
    __syncthreads();
    float zr[16];
#pragma unroll
    for (int j = 0; j < 16; ++j) zr[j] = zrow[l + 64 * j];
    double dmin = 1e300;
    int cmin = 0x7fffffff;
    for (int ci = 0; ci < 1024; ++ci) {
      const int c = wid * 1024 + ci;
      const float* e = embed + (size_t)c * CDIM;
      double dd = 0.0;
#pragma unroll
      for (int j = 0; j < 16; ++j) {
        const double df = (double)zr[j] - (double)e[l + 64 * j];
        dd = fma(df, df, dd);
      }
#pragma unroll
      for (int o = 32; o > 0; o >>= 1) dd += __shfl_xor(dd, o);
      if (dd < dmin) { dmin = dd; cmin = c; }
    }
    if (l == 0) { wd[wid] = dmin; wcidx[wid] = cmin; }
    __syncthreads();
    if (t == 0) {
      double dm = wd[0]; int cm = wcidx[0];
#pragma unroll
      for (int wv = 1; wv < 4; ++wv) {
        if (wd[wv] < dm || (wd[wv] == dm && wcidx[wv] < cm)) {
          dm = wd[wv]; cm = wcidx[wv];
        }
      }
      idxf[grow] = cm;
      out_idx[grow] = (float)cm;
      crow[grow] = (float)dm;
    }
    __syncthreads();
  }
}

// ---------------- K4: E_post = embed @ w_post ----------------
__global__ __launch_bounds__(256) void k_epost(const float* __restrict__ E,
                                               const float* __restrict__ w_post,
                                               float* __restrict__ E_post) {
  __shared__ float es[16][128];
  const int t = threadIdx.x;
  const int r0 = blockIdx.x * 16;
  float acc[16];
#pragma unroll
  for (int r = 0; r < 16; ++r) acc[r] = 0.f;
  for (int k0 = 0; k0 < CDIM; k0 += 128) {
    __syncthreads();
#pragma unroll
    for (int p = 0; p < 2; ++p) {
      const int fl = (p * 256 + t) * 4;
      const int r = fl >> 7, kk = fl & 127;
      float4 v = *(const float4*)(E + (size_t)(r0 + r) * CDIM + k0 + kk);
      *(float4*)&es[r][kk] = v;
    }
    __syncthreads();
#pragma unroll 4
    for (int d = 0; d < 128; ++d) {
      const float w = w_post[(size_t)(k0 + d) * DIMX + t];
#pragma unroll
      for (int r = 0; r < 16; ++r) acc[r] = fmaf(es[r][d], w, acc[r]);
    }
  }
#pragma unroll
  for (int r = 0; r < 16; ++r)
    E_post[(size_t)(r0 + r) * DIMX + t] = acc[r];
}

// ---------------- K5: gather E_post rows + bias ----------------
__global__ __launch_bounds__(256) void k_gather(const float* __restrict__ E_post,
                                                const int* __restrict__ idx,
                                                const float* __restrict__ b_post,
                                                float* __restrict__ outq) {
  const int t = threadIdx.x;
  const int r0 = blockIdx.x * 16;
  const float bp = b_post[t];
#pragma unroll
  for (int i = 0; i < 16; ++i) {
    const int row = r0 + i;
    outq[(size_t)row * DIMX + t] = E_post[(size_t)idx[row] * DIMX + t] + bp;
  }
}

// ---------------- K6: commit reduce ----------------
__global__ __launch_bounds__(256) void k_commit_final(
    const float* __restrict__ crow, float* __restrict__ out_commit) {
  const int t = threadIdx.x;
  double s = 0.0;
  for (int i = t; i < BN_ROWS; i += 256) s += (double)crow[i];
#pragma unroll
  for (int o = 32; o > 0; o >>= 1) s += __shfl_xor(s, o);
  __shared__ double wsum[4];
  if ((t & 63) == 0) wsum[t >> 6] = s;
  __syncthreads();
  if (t == 0)
    *out_commit = (float)(0.25 * (wsum[0] + wsum[1] + wsum[2] + wsum[3]) /
                          (65536.0 * 1024.0));
}

extern "C" void kernel_launch(void* const* d_in, const int* in_sizes, int n_in,
                              void* d_out, int out_size, void* d_ws,
                              size_t ws_size, hipStream_t stream) {
  const float* x = (const float*)d_in[0];
  const float* ln_g = (const float*)d_in[1];
  const float* ln_b = (const float*)d_in[2];
  const float* w_pre = (const float*)d_in[3];
  const float* b_pre = (const float*)d_in[4];
  const float* embed = (const float*)d_in[5];
  const float* w_post = (const float*)d_in[6];
  const float* b_post = (const float*)d_in[7];

  float* out = (float*)d_out;
  float* outq = out;                   // 16777216 f32
  float* out_idx = out + 16777216;     // 65536 f32
  float* out_commit = out + 16842752;  // 1 f32

  char* ws = (char*)d_ws;
  float* e_sq = (float*)(ws + OFF_ESQ);
  float* z_sq = (float*)(ws + OFF_ZSQ);
  int* idxf = (int*)(ws + OFF_IDXF);
  float* crow = (float*)(ws + OFF_CROW);
  float* E_post = (float*)(ws + OFF_EPOST);
  short* Eh = (short*)(ws + OFF_EH);
  short* El = (short*)(ws + OFF_EL);
  int* nflag = (int*)(ws + OFF_NFLAG);
  int* flag_rows = (int*)(ws + OFF_FLAG);

  // chunk rows sized to ws: per-row = 512B (32 partials) + 4096B (zh+zl)
  int chunk = 4096;
  while (chunk < BN_ROWS &&
         OFF_PART + (size_t)(chunk * 2) * 4608ull <= ws_size)
    chunk *= 2;
  unsigned long long* part = (unsigned long long*)(ws + OFF_PART);
  short* zh = (short*)(ws + OFF_PART + (size_t)chunk * 512);
  short* zl = (short*)(ws + OFF_PART + (size_t)chunk * 512 + (size_t)chunk * 2048);

  hipMemsetAsync(nflag, 0, sizeof(int), stream);
  k_esq<<<KCODES / 4, 256, 0, stream>>>(embed, e_sq);
  k_ehilo<<<KCODES, 256, 0, stream>>>(embed, Eh, El);
  k_epost<<<KCODES / 16, 256, 0, stream>>>(embed, w_post, E_post);

  for (int row0 = 0; row0 < BN_ROWS; row0 += chunk) {
    k_ln_gelu_gemm<<<chunk / 16, 256, 0, stream>>>(x, ln_g, ln_b, w_pre, b_pre,
                                                   zh, zl, z_sq, row0);
    k_score<<<(chunk / 128) * 32, 256, 0, stream>>>(Eh, El, zh, zl, e_sq, part,
                                                    chunk);
    k_combine<<<(chunk + 255) / 256, 256, 0, stream>>>(part, z_sq, idxf, crow,
                                                       out_idx, flag_rows,
                                                       nflag, chunk, row0);
  }

  k_exact<<<1024, 256, 0, stream>>>(x, ln_g, ln_b, w_pre, b_pre, embed,
                                    flag_rows, nflag, idxf, crow, out_idx);
  k_gather<<<BN_ROWS / 16, 256, 0, stream>>>(E_post, idxf, b_post, outq);
  k_commit_final<<<1, 256, 0, stream>>>(crow, out_commit);
}

// Round 6
// 2966.785 us; speedup vs baseline: 3.6811x; 1.2121x over previous
//
#include <hip/hip_runtime.h>

#define BN_ROWS 65536
#define DIMX 256
#define CDIM 1024
#define KCODES 4096
#define MARGIN 0.03f
#define FLT_BIG 3.402823466e+38f
#define NSP 16  // code strips of 256

// ---------------- ws layout (bytes) ----------------
static const size_t OFF_ESQ   = 0;          // 4096 f32 (16KB)
static const size_t OFF_ZSQ   = 16384;      // 65536 f32
static const size_t OFF_IDXF  = 278528;     // 65536 i32
static const size_t OFF_CROW  = 540672;     // 65536 f32
static const size_t OFF_EPOST = 802816;     // 4096*256 f32 (4MB)
static const size_t OFF_EH    = 4997120;    // 4096*1024 bf16 (8MB)
static const size_t OFF_EL    = 13385728;   // 4096*1024 bf16 (8MB)
static const size_t OFF_NFLAG = 21774336;   // 1 i32 (+pad 64B)
static const size_t OFF_FLAG  = 21774400;   // 65536 i32 (256KB)
static const size_t OFF_PART  = 22036544;   // NSP * chunk * 16B
// zh = OFF_PART + chunk*256 ; zl = zh + chunk*2048

typedef __attribute__((ext_vector_type(8))) short bf16x8;
typedef __attribute__((ext_vector_type(4))) float f32x4;

#define GLOAD_LDS16(gsrc, ldst)                                                \
  __builtin_amdgcn_global_load_lds(                                            \
      (const __attribute__((address_space(1))) void*)(gsrc),                   \
      (__attribute__((address_space(3))) void*)(ldst), 16, 0, 0)

__device__ inline unsigned short bf_rtn(float f) {
  unsigned u = __float_as_uint(f);
  unsigned r = (u + 0x7FFFu + ((u >> 16) & 1u)) >> 16;
  return (unsigned short)r;
}
__device__ inline void bf_split(float f, unsigned short& h, unsigned short& l) {
  h = bf_rtn(f);
  float hf = __uint_as_float(((unsigned)h) << 16);
  l = bf_rtn(f - hf);
}
__device__ inline unsigned fkey(float s) {
  unsigned b = __float_as_uint(s);
  return b ^ ((unsigned)((int)b >> 31) | 0x80000000u);
}
__device__ inline float keyinv(unsigned k) {
  unsigned b = (k & 0x80000000u) ? (k ^ 0x80000000u) : ~k;
  return __uint_as_float(b);
}
__device__ inline void merge2(unsigned long long& a1, unsigned long long& a2,
                              unsigned long long b1, unsigned long long b2) {
  unsigned long long n1 = a1 < b1 ? a1 : b1;
  unsigned long long hi = a1 < b1 ? b1 : a1;
  unsigned long long m = a2 < b2 ? a2 : b2;
  a2 = hi < m ? hi : m;
  a1 = n1;
}

// ---------------- K0: e_sq ----------------
__global__ __launch_bounds__(256) void k_esq(const float* __restrict__ embed,
                                             float* __restrict__ e_sq) {
  const int t = threadIdx.x, wv = t >> 6, lane = t & 63;
  const int row = blockIdx.x * 4 + wv;
  const float* e = embed + (size_t)row * CDIM;
  float s = 0.f;
  for (int k = lane * 4; k < CDIM; k += 256) {
    float4 v = *(const float4*)(e + k);
    s = fmaf(v.x, v.x, s); s = fmaf(v.y, v.y, s);
    s = fmaf(v.z, v.z, s); s = fmaf(v.w, v.w, s);
  }
#pragma unroll
  for (int o = 32; o > 0; o >>= 1) s += __shfl_xor(s, o);
  if (lane == 0) e_sq[row] = s;
}

// ---------------- K0b: E -> hi/lo bf16 ----------------
__global__ __launch_bounds__(256) void k_ehilo(const float* __restrict__ embed,
                                               short* __restrict__ Eh,
                                               short* __restrict__ El) {
  const int t = threadIdx.x;
  const size_t row = blockIdx.x;
  float4 v = *(const float4*)(embed + row * CDIM + t * 4);
  unsigned short h0, l0, h1, l1, h2, l2, h3, l3;
  bf_split(v.x, h0, l0); bf_split(v.y, h1, l1);
  bf_split(v.z, h2, l2); bf_split(v.w, h3, l3);
  *(short4*)(Eh + row * CDIM + t * 4) =
      make_short4((short)h0, (short)h1, (short)h2, (short)h3);
  *(short4*)(El + row * CDIM + t * 4) =
      make_short4((short)l0, (short)l1, (short)l2, (short)l3);
}

// ---------------- K1: LN + GELU + @w_pre -> z hi/lo + z_sq ----------------
__global__ __launch_bounds__(256) void k_ln_gelu_gemm(
    const float* __restrict__ x, const float* __restrict__ ln_g,
    const float* __restrict__ ln_b, const float* __restrict__ w_pre,
    const float* __restrict__ b_pre, short* __restrict__ zh,
    short* __restrict__ zl, float* __restrict__ z_sq, int row0) {
  __shared__ float g[16][DIMX];
  const int t = threadIdx.x;
  const int lrow0 = blockIdx.x * 16;
  const int grow0 = row0 + lrow0;
  const int wv = t >> 6, lane = t & 63;
#pragma unroll
  for (int j = 0; j < 4; ++j) {
    const int r = wv * 4 + j;
    const float* xr = x + (size_t)(grow0 + r) * DIMX;
    float4 v = *(const float4*)(xr + lane * 4);
    float s = v.x + v.y + v.z + v.w;
    float ss = v.x * v.x + v.y * v.y + v.z * v.z + v.w * v.w;
#pragma unroll
    for (int o = 32; o > 0; o >>= 1) { s += __shfl_xor(s, o); ss += __shfl_xor(ss, o); }
    const float mu = s * (1.0f / 256.0f);
    const float var = ss * (1.0f / 256.0f) - mu * mu;
    const float rstd = rsqrtf(var + 1e-5f);
    float vv[4] = {v.x, v.y, v.z, v.w};
#pragma unroll
    for (int q = 0; q < 4; ++q) {
      const int d = lane * 4 + q;
      float xn = (vv[q] - mu) * rstd * ln_g[d] + ln_b[d];
      g[r][d] = 0.5f * xn * (1.0f + erff(xn * 0.70710678118654752f));
    }
  }
  __syncthreads();
  float acc[16][4];
#pragma unroll
  for (int r = 0; r < 16; ++r)
#pragma unroll
    for (int c = 0; c < 4; ++c) acc[r][c] = 0.f;
#pragma unroll 4
  for (int d = 0; d < DIMX; ++d) {
    float4 w = *(const float4*)(w_pre + (size_t)d * CDIM + t * 4);
#pragma unroll
    for (int r = 0; r < 16; ++r) {
      const float gv = g[r][d];
      acc[r][0] = fmaf(gv, w.x, acc[r][0]);
      acc[r][1] = fmaf(gv, w.y, acc[r][1]);
      acc[r][2] = fmaf(gv, w.z, acc[r][2]);
      acc[r][3] = fmaf(gv, w.w, acc[r][3]);
    }
  }
  float4 bp = *(const float4*)(b_pre + t * 4);
  float ps[16];
#pragma unroll
  for (int r = 0; r < 16; ++r) {
    float4 o;
    o.x = acc[r][0] + bp.x; o.y = acc[r][1] + bp.y;
    o.z = acc[r][2] + bp.z; o.w = acc[r][3] + bp.w;
    unsigned short h0, l0, h1, l1, h2, l2, h3, l3;
    bf_split(o.x, h0, l0); bf_split(o.y, h1, l1);
    bf_split(o.z, h2, l2); bf_split(o.w, h3, l3);
    *(short4*)(zh + (size_t)(lrow0 + r) * CDIM + t * 4) =
        make_short4((short)h0, (short)h1, (short)h2, (short)h3);
    *(short4*)(zl + (size_t)(lrow0 + r) * CDIM + t * 4) =
        make_short4((short)l0, (short)l1, (short)l2, (short)l3);
    ps[r] = o.x * o.x + o.y * o.y + o.z * o.z + o.w * o.w;
  }
#pragma unroll
  for (int r = 0; r < 16; ++r)
#pragma unroll
    for (int o = 32; o > 0; o >>= 1) ps[r] += __shfl_xor(ps[r], o);
  __shared__ float zps[4][16];
  if (lane == 0)
#pragma unroll
    for (int r = 0; r < 16; ++r) zps[wv][r] = ps[r];
  __syncthreads();
  if (t < 16) z_sq[grow0 + t] = zps[0][t] + zps[1][t] + zps[2][t] + zps[3][t];
}

// ---------------- K2: bf16x3 MFMA score GEMM, 256x256 tile, phased ----------
// grid = (chunk/256)*NSP ; block = 512 (8 waves: 2 M-halves x 4 N-quarters)
// LDS buffer layout (shorts): Ah[frag 0..15]*512 | Al +8192 | Bh +16384 | Bl +24576
__global__ __launch_bounds__(512, 2) void k_score(
    const short* __restrict__ Eh, const short* __restrict__ El,
    const short* __restrict__ Zh, const short* __restrict__ Zl,
    const float* __restrict__ e_sq, unsigned long long* __restrict__ part,
    int chunk) {
  __shared__ __align__(16) short lds[2][32768];  // 2 x 64KB
  const int t = threadIdx.x;
  const int cpx = gridDim.x >> 3;  // bijective XCD swizzle, grid % 8 == 0
  const int bx = (blockIdx.x & 7) * cpx + (blockIdx.x >> 3);
  const int zblk = bx / NSP, csp = bx % NSP;
  const int wid = t >> 6, l = t & 63;
  const int wr = wid >> 2, wc = wid & 3;
  const int lg = l >> 4, lo16 = l & 15;
  const int rowbase = zblk * 256;
  const int m0 = csp * 256;
  const int wr8 = wr * 8, wc4 = wc * 4, l8 = l * 8;

  // staging: wave wid owns LDS region wid*4096 shorts (8 frags of 512)
  const short* sarr = (wid < 2) ? Eh : (wid < 4) ? El : (wid < 6) ? Zh : Zl;
  const int sbase = (wid < 4) ? m0 : rowbase;
  const int shalf = wid & 1;
  const short* sp0 =
      sarr + (size_t)(sbase + shalf * 128 + lo16) * 1024 + lg * 8;

  f32x4 acc[8][4];
#pragma unroll
  for (int mi = 0; mi < 8; ++mi)
#pragma unroll
    for (int ni = 0; ni < 4; ++ni) acc[mi][ni] = (f32x4){0.f, 0.f, 0.f, 0.f};

  // prologue: stage kt=0 into buf 0, full drain once
  {
    short* D = &lds[0][wid * 4096];
#pragma unroll
    for (int u = 0; u < 8; ++u) GLOAD_LDS16(sp0 + u * 16384, D + u * 512);
  }
  asm volatile("s_waitcnt vmcnt(0)" ::: "memory");
  __builtin_amdgcn_s_barrier();
  __builtin_amdgcn_sched_barrier(0);

  for (int kt = 0; kt < 32; ++kt) {
    const int cur = kt & 1;
    const short* Lc = lds[cur];
    short* Dst = &lds[cur ^ 1][wid * 4096];
    const short* spk = sp0 + (kt + 1) * 32;
    const bool st = (kt < 31);

    bf16x8 bh[4], bl[4];
#pragma unroll
    for (int ni = 0; ni < 4; ++ni) {
      bh[ni] = *(const bf16x8*)(Lc + 16384 + (wc4 + ni) * 512 + l8);
      bl[ni] = *(const bf16x8*)(Lc + 24576 + (wc4 + ni) * 512 + l8);
    }
#pragma unroll
    for (int p = 0; p < 4; ++p) {
      const int mi0 = 2 * p;
      bf16x8 a0h = *(const bf16x8*)(Lc + (wr8 + mi0) * 512 + l8);
      bf16x8 a0l = *(const bf16x8*)(Lc + 8192 + (wr8 + mi0) * 512 + l8);
      bf16x8 a1h = *(const bf16x8*)(Lc + (wr8 + mi0 + 1) * 512 + l8);
      bf16x8 a1l = *(const bf16x8*)(Lc + 8192 + (wr8 + mi0 + 1) * 512 + l8);
      if (p < 2 && st) {
        // issue next-K-tile loads early (counted in flight across phases)
#pragma unroll
        for (int u = 0; u < 4; ++u)
          GLOAD_LDS16(spk + (p * 4 + u) * 16384, Dst + (p * 4 + u) * 512);
      }
      __builtin_amdgcn_s_barrier();
      asm volatile("s_waitcnt lgkmcnt(0)" ::: "memory");
      __builtin_amdgcn_sched_barrier(0);
      __builtin_amdgcn_s_setprio(1);
#pragma unroll
      for (int ni = 0; ni < 4; ++ni) {
        f32x4 c0 = acc[mi0][ni];
        f32x4 c1 = acc[mi0 + 1][ni];
        c0 = __builtin_amdgcn_mfma_f32_16x16x32_bf16(a0h, bh[ni], c0, 0, 0, 0);
        c0 = __builtin_amdgcn_mfma_f32_16x16x32_bf16(a0h, bl[ni], c0, 0, 0, 0);
        c0 = __builtin_amdgcn_mfma_f32_16x16x32_bf16(a0l, bh[ni], c0, 0, 0, 0);
        c1 = __builtin_amdgcn_mfma_f32_16x16x32_bf16(a1h, bh[ni], c1, 0, 0, 0);
        c1 = __builtin_amdgcn_mfma_f32_16x16x32_bf16(a1h, bl[ni], c1, 0, 0, 0);
        c1 = __builtin_amdgcn_mfma_f32_16x16x32_bf16(a1l, bh[ni], c1, 0, 0, 0);
        acc[mi0][ni] = c0;
        acc[mi0 + 1][ni] = c1;
      }
      __builtin_amdgcn_s_setprio(0);
      if (p == 3) asm volatile("s_waitcnt vmcnt(0)" ::: "memory");
      __builtin_amdgcn_s_barrier();
      __builtin_amdgcn_sched_barrier(0);
    }
  }

  // epilogue: scores + per-row top-2 over this block's 256 codes
  float s1[4], s2[4];
  int i1[4], i2[4];
#pragma unroll
  for (int i = 0; i < 4; ++i) {
    s1[i] = FLT_BIG; s2[i] = FLT_BIG; i1[i] = 0x7fffffff; i2[i] = 0x7fffffff;
  }
#pragma unroll
  for (int mi = 0; mi < 8; ++mi) {
    const int c0 = m0 + wr * 128 + mi * 16 + lg * 4;
    float4 es = *(const float4*)(e_sq + c0);
    float esv[4] = {es.x, es.y, es.z, es.w};
#pragma unroll
    for (int ni = 0; ni < 4; ++ni) {
#pragma unroll
      for (int j = 0; j < 4; ++j) {
        const float s = fmaf(-2.0f, acc[mi][ni][j], esv[j]);
        const int c = c0 + j;
        if (s < s1[ni]) {
          s2[ni] = s1[ni]; i2[ni] = i1[ni]; s1[ni] = s; i1[ni] = c;
        } else if (s < s2[ni]) {
          s2[ni] = s; i2[ni] = c;
        }
      }
    }
  }

  unsigned long long* red = (unsigned long long*)lds;
#pragma unroll
  for (int ni = 0; ni < 4; ++ni) {
    unsigned long long k1v =
        (((unsigned long long)fkey(s1[ni])) << 32) | (unsigned)i1[ni];
    unsigned long long k2v =
        (((unsigned long long)fkey(s2[ni])) << 32) | (unsigned)i2[ni];
    unsigned long long o1 = __shfl_xor(k1v, 16), o2 = __shfl_xor(k2v, 16);
    merge2(k1v, k2v, o1, o2);
    o1 = __shfl_xor(k1v, 32); o2 = __shfl_xor(k2v, 32);
    merge2(k1v, k2v, o1, o2);
    if (lg == 0) {
      const int r = wc * 64 + ni * 16 + lo16;  // block-local z-row
      red[(r * 2 + wr) * 2 + 0] = k1v;
      red[(r * 2 + wr) * 2 + 1] = k2v;
    }
  }
  __syncthreads();
  if (t < 256) {
    unsigned long long a1 = red[(t * 2 + 0) * 2 + 0];
    unsigned long long a2 = red[(t * 2 + 0) * 2 + 1];
    merge2(a1, a2, red[(t * 2 + 1) * 2 + 0], red[(t * 2 + 1) * 2 + 1]);
    unsigned long long* pp = part + ((size_t)csp * chunk + rowbase + t) * 2;
    pp[0] = a1; pp[1] = a2;
  }
}

// ---------------- K3a: combine partials, flag near-ties ----------------
__global__ __launch_bounds__(256) void k_combine(
    const unsigned long long* __restrict__ part, const float* __restrict__ z_sq,
    int* __restrict__ idxf, float* __restrict__ crow,
    float* __restrict__ out_idx, int* __restrict__ flag_rows,
    int* __restrict__ nflag, int chunk, int row0) {
  const int lrow = blockIdx.x * 256 + threadIdx.x;
  if (lrow >= chunk) return;
  const int grow = row0 + lrow;
  unsigned long long b1 = part[(size_t)lrow * 2];
  unsigned long long b2 = part[(size_t)lrow * 2 + 1];
#pragma unroll
  for (int sp = 1; sp < NSP; ++sp)
    merge2(b1, b2, part[((size_t)sp * chunk + lrow) * 2],
           part[((size_t)sp * chunk + lrow) * 2 + 1]);
  const float s1 = keyinv((unsigned)(b1 >> 32));
  const float s2 = keyinv((unsigned)(b2 >> 32));
  const int fin = (int)(b1 & 0xFFFFFFFFull);
  idxf[grow] = fin;
  out_idx[grow] = (float)fin;
  crow[grow] = z_sq[grow] + s1;
  if (s2 - s1 < MARGIN) {
    const int slot = atomicAdd(nflag, 1);
    flag_rows[slot] = grow;
  }
}

// ---------------- K3b: exact f64 full rescan of flagged rows ----------------
__global__ __launch_bounds__(256) void k_exact(
    const float* __restrict__ x, const float* __restrict__ ln_g,
    const float* __restrict__ ln_b, const float* __restrict__ w_pre,
    const float* __restrict__ b_pre, const float* __restrict__ embed,
    const int* __restrict__ flag_rows, const int* __restrict__ nflag,
    int* __restrict__ idxf, float* __restrict__ crow,
    float* __restrict__ out_idx) {
  __shared__ float gsh[256];
  __shared__ float zrow[1024];
  __shared__ double wd[4];
  __shared__ int wcidx[4];
  const int t = threadIdx.x;
  const int wid = t >> 6, l = t & 63;
  const int n = *nflag;

  for (int fi = blockIdx.x; fi < n; fi += gridDim.x) {
    const int grow = flag_rows[fi];
    if (t < 64) {
      float4 v = *(const float4*)(x + (size_t)grow * DIMX + t * 4);
      float s = v.x + v.y + v.z + v.w;
      float ss = v.x * v.x + v.y * v.y + v.z * v.z + v.w * v.w;
#pragma unroll
      for (int o = 32; o > 0; o >>= 1) { s += __shfl_xor(s, o); ss += __shfl_xor(ss, o); }
      const float mu = s * (1.0f / 256.0f);
      const float var = ss * (1.0f / 256.0f) - mu * mu;
      const float rstd = rsqrtf(var + 1e-5f);
      float vv[4] = {v.x, v.y, v.z, v.w};
#pragma unroll
      for (int q = 0; q < 4; ++q) {
        const int d = t * 4 + q;
        float xn = (vv[q] - mu) * rstd * ln_g[d] + ln_b[d];
        gsh[d] = 0.5f * xn * (1.0f + erff(xn * 0.70710678118654752f));
      }
    }
    __syncthreads();
    float a0 = 0.f, a1f = 0.f, a2f = 0.f, a3f = 0.f;
    for (int d = 0; d < DIMX; ++d) {
      float4 w = *(const float4*)(w_pre + (size_t)d * CDIM + t * 4);
      const float gv = gsh[d];
      a0 = fmaf(gv, w.x, a0); a1f = fmaf(gv, w.y, a1f);
      a2f = fmaf(gv, w.z, a2f); a3f = fmaf(gv, w.w, a3f);
    }
    float4 bp = *(const float4*)(b_pre + t * 4);
    zrow[t * 4 + 0] = a0 + bp.x; zrow[t * 4 + 1] = a1f + bp.y;
    zrow[t * 4 + 2] = a2f + bp.z; zrow[t * 4 + 3] = a3f + bp.w;
    __syncthreads();
    float zr[16];
#pragma unroll
    for (int j = 0; j < 16; ++j) zr[j] = zrow[l + 64 * j];
    double dmin = 1e300;
    int cmin = 0x7fffffff;
    for (int ci = 0; ci < 1024; ++ci) {
      const int c = wid * 1024 + ci;
      const float* e = embed + (size_t)c * CDIM;
      double dd = 0.0;
#pragma unroll
      for (int j = 0; j < 16; ++j) {
        const double df = (double)zr[j] - (double)e[l + 64 * j];
        dd = fma(df, df, dd);
      }
#pragma unroll
      for (int o = 32; o > 0; o >>= 1) dd += __shfl_xor(dd, o);
      if (dd < dmin) { dmin = dd; cmin = c; }
    }
    if (l == 0) { wd[wid] = dmin; wcidx[wid] = cmin; }
    __syncthreads();
    if (t == 0) {
      double dm = wd[0]; int cm = wcidx[0];
#pragma unroll
      for (int wv = 1; wv < 4; ++wv) {
        if (wd[wv] < dm || (wd[wv] == dm && wcidx[wv] < cm)) {
          dm = wd[wv]; cm = wcidx[wv];
        }
      }
      idxf[grow] = cm;
      out_idx[grow] = (float)cm;
      crow[grow] = (float)dm;
    }
    __syncthreads();
  }
}

// ---------------- K4: E_post = embed @ w_post ----------------
__global__ __launch_bounds__(256) void k_epost(const float* __restrict__ E,
                                               const float* __restrict__ w_post,
                                               float* __restrict__ E_post) {
  __shared__ float es[16][128];
  const int t = threadIdx.x;
  const int r0 = blockIdx.x * 16;
  float acc[16];
#pragma unroll
  for (int r = 0; r < 16; ++r) acc[r] = 0.f;
  for (int k0 = 0; k0 < CDIM; k0 += 128) {
    __syncthreads();
#pragma unroll
    for (int p = 0; p < 2; ++p) {
      const int fl = (p * 256 + t) * 4;
      const int r = fl >> 7, kk = fl & 127;
      float4 v = *(const float4*)(E + (size_t)(r0 + r) * CDIM + k0 + kk);
      *(float4*)&es[r][kk] = v;
    }
    __syncthreads();
#pragma unroll 4
    for (int d = 0; d < 128; ++d) {
      const float w = w_post[(size_t)(k0 + d) * DIMX + t];
#pragma unroll
      for (int r = 0; r < 16; ++r) acc[r] = fmaf(es[r][d], w, acc[r]);
    }
  }
#pragma unroll
  for (int r = 0; r < 16; ++r)
    E_post[(size_t)(r0 + r) * DIMX + t] = acc[r];
}

// ---------------- K5: gather E_post rows + bias ----------------
__global__ __launch_bounds__(256) void k_gather(const float* __restrict__ E_post,
                                                const int* __restrict__ idx,
                                                const float* __restrict__ b_post,
                                                float* __restrict__ outq) {
  const int t = threadIdx.x;
  const int r0 = blockIdx.x * 16;
  const float bp = b_post[t];
#pragma unroll
  for (int i = 0; i < 16; ++i) {
    const int row = r0 + i;
    outq[(size_t)row * DIMX + t] = E_post[(size_t)idx[row] * DIMX + t] + bp;
  }
}

// ---------------- K6: commit reduce ----------------
__global__ __launch_bounds__(256) void k_commit_final(
    const float* __restrict__ crow, float* __restrict__ out_commit) {
  const int t = threadIdx.x;
  double s = 0.0;
  for (int i = t; i < BN_ROWS; i += 256) s += (double)crow[i];
#pragma unroll
  for (int o = 32; o > 0; o >>= 1) s += __shfl_xor(s, o);
  __shared__ double wsum[4];
  if ((t & 63) == 0) wsum[t >> 6] = s;
  __syncthreads();
  if (t == 0)
    *out_commit = (float)(0.25 * (wsum[0] + wsum[1] + wsum[2] + wsum[3]) /
                          (65536.0 * 1024.0));
}

extern "C" void kernel_launch(void* const* d_in, const int* in_sizes, int n_in,
                              void* d_out, int out_size, void* d_ws,
                              size_t ws_size, hipStream_t stream) {
  const float* x = (const float*)d_in[0];
  const float* ln_g = (const float*)d_in[1];
  const float* ln_b = (const float*)d_in[2];
  const float* w_pre = (const float*)d_in[3];
  const float* b_pre = (const float*)d_in[4];
  const float* embed = (const float*)d_in[5];
  const float* w_post = (const float*)d_in[6];
  const float* b_post = (const float*)d_in[7];

  float* out = (float*)d_out;
  float* outq = out;                   // 16777216 f32
  float* out_idx = out + 16777216;     // 65536 f32
  float* out_commit = out + 16842752;  // 1 f32

  char* ws = (char*)d_ws;
  float* e_sq = (float*)(ws + OFF_ESQ);
  float* z_sq = (float*)(ws + OFF_ZSQ);
  int* idxf = (int*)(ws + OFF_IDXF);
  float* crow = (float*)(ws + OFF_CROW);
  float* E_post = (float*)(ws + OFF_EPOST);
  short* Eh = (short*)(ws + OFF_EH);
  short* El = (short*)(ws + OFF_EL);
  int* nflag = (int*)(ws + OFF_NFLAG);
  int* flag_rows = (int*)(ws + OFF_FLAG);

  // chunk rows sized to ws: per-row = 256B (16 partials) + 4096B (zh+zl)
  int chunk = 4096;
  while (chunk < BN_ROWS &&
         OFF_PART + (size_t)(chunk * 2) * 4352ull <= ws_size)
    chunk *= 2;
  unsigned long long* part = (unsigned long long*)(ws + OFF_PART);
  short* zh = (short*)(ws + OFF_PART + (size_t)chunk * 256);
  short* zl = (short*)(ws + OFF_PART + (size_t)chunk * 256 + (size_t)chunk * 2048);

  hipMemsetAsync(nflag, 0, sizeof(int), stream);
  k_esq<<<KCODES / 4, 256, 0, stream>>>(embed, e_sq);
  k_ehilo<<<KCODES, 256, 0, stream>>>(embed, Eh, El);
  k_epost<<<KCODES / 16, 256, 0, stream>>>(embed, w_post, E_post);

  for (int row0 = 0; row0 < BN_ROWS; row0 += chunk) {
    k_ln_gelu_gemm<<<chunk / 16, 256, 0, stream>>>(x, ln_g, ln_b, w_pre, b_pre,
                                                   zh, zl, z_sq, row0);
    k_score<<<(chunk / 256) * NSP, 512, 0, stream>>>(Eh, El, zh, zl, e_sq,
                                                     part, chunk);
    k_combine<<<(chunk + 255) / 256, 256, 0, stream>>>(part, z_sq, idxf, crow,
                                                       out_idx, flag_rows,
                                                       nflag, chunk, row0);
  }

  k_exact<<<1024, 256, 0, stream>>>(x, ln_g, ln_b, w_pre, b_pre, embed,
                                    flag_rows, nflag, idxf, crow, out_idx);
  k_gather<<<BN_ROWS / 16, 256, 0, stream>>>(E_post, idxf, b_post, outq);
  k_commit_final<<<1, 256, 0, stream>>>(crow, out_commit);
}

// Round 7
// 2391.906 us; speedup vs baseline: 4.5658x; 1.2403x over previous
//
#include <hip/hip_runtime.h>

#define BN_ROWS 65536
#define DIMX 256
#define CDIM 1024
#define KCODES 4096
#define NSP 16          // code strips of 256
#define CMARG 2.5f      // coarse capture margin (~18 sigma)
#define FLT_BIG 3.402823466e+38f

// ---------------- ws layout (bytes) ----------------
static const size_t OFF_ESQ   = 0;          // 4096 f32 (16KB)
static const size_t OFF_ZSQ   = 16384;      // 65536 f32 (k1 side-output, unused)
static const size_t OFF_IDXF  = 278528;     // 65536 i32
static const size_t OFF_CROW  = 540672;     // 65536 f32
static const size_t OFF_EPOST = 802816;     // 4096*256 f32 (4MB)
static const size_t OFF_EH    = 4997120;    // 4096*1024 bf16 (8MB)
static const size_t OFF_NFLAG = 13385728;   // 1 i32 (+pad)
static const size_t OFF_FLAG  = 13385792;   // 65536 i32
static const size_t OFF_CAND  = 13647936;   // NSP * chunk * 4 slots * 8B
// zh = OFF_CAND + chunk*512 ; zl = zh + chunk*2048

typedef __attribute__((ext_vector_type(8))) short bf16x8;
typedef __attribute__((ext_vector_type(4))) float f32x4;

#define GLOAD_LDS16(gsrc, ldst)                                                \
  __builtin_amdgcn_global_load_lds(                                            \
      (const __attribute__((address_space(1))) void*)(gsrc),                   \
      (__attribute__((address_space(3))) void*)(ldst), 16, 0, 0)

__device__ inline unsigned short bf_rtn(float f) {
  unsigned u = __float_as_uint(f);
  unsigned r = (u + 0x7FFFu + ((u >> 16) & 1u)) >> 16;
  return (unsigned short)r;
}
__device__ inline void bf_split(float f, unsigned short& h, unsigned short& l) {
  h = bf_rtn(f);
  float hf = __uint_as_float(((unsigned)h) << 16);
  l = bf_rtn(f - hf);
}
__device__ inline unsigned fkey(float s) {
  unsigned b = __float_as_uint(s);
  return b ^ ((unsigned)((int)b >> 31) | 0x80000000u);
}
__device__ inline float keyinv(unsigned k) {
  unsigned b = (k & 0x80000000u) ? (k ^ 0x80000000u) : ~k;
  return __uint_as_float(b);
}

// ---------------- K0: e_sq ----------------
__global__ __launch_bounds__(256) void k_esq(const float* __restrict__ embed,
                                             float* __restrict__ e_sq) {
  const int t = threadIdx.x, wv = t >> 6, lane = t & 63;
  const int row = blockIdx.x * 4 + wv;
  const float* e = embed + (size_t)row * CDIM;
  float s = 0.f;
  for (int k = lane * 4; k < CDIM; k += 256) {
    float4 v = *(const float4*)(e + k);
    s = fmaf(v.x, v.x, s); s = fmaf(v.y, v.y, s);
    s = fmaf(v.z, v.z, s); s = fmaf(v.w, v.w, s);
  }
#pragma unroll
  for (int o = 32; o > 0; o >>= 1) s += __shfl_xor(s, o);
  if (lane == 0) e_sq[row] = s;
}

// ---------------- K0b: E -> hi bf16 only ----------------
__global__ __launch_bounds__(256) void k_ehi(const float* __restrict__ embed,
                                             short* __restrict__ Eh) {
  const int t = threadIdx.x;
  const size_t row = blockIdx.x;
  float4 v = *(const float4*)(embed + row * CDIM + t * 4);
  *(short4*)(Eh + row * CDIM + t * 4) =
      make_short4((short)bf_rtn(v.x), (short)bf_rtn(v.y), (short)bf_rtn(v.z),
                  (short)bf_rtn(v.w));
}

// ---------------- K1: LN + GELU + @w_pre -> z hi/lo + z_sq ----------------
__global__ __launch_bounds__(256) void k_ln_gelu_gemm(
    const float* __restrict__ x, const float* __restrict__ ln_g,
    const float* __restrict__ ln_b, const float* __restrict__ w_pre,
    const float* __restrict__ b_pre, short* __restrict__ zh,
    short* __restrict__ zl, float* __restrict__ z_sq, int row0) {
  __shared__ float g[16][DIMX];
  const int t = threadIdx.x;
  const int lrow0 = blockIdx.x * 16;
  const int grow0 = row0 + lrow0;
  const int wv = t >> 6, lane = t & 63;
#pragma unroll
  for (int j = 0; j < 4; ++j) {
    const int r = wv * 4 + j;
    const float* xr = x + (size_t)(grow0 + r) * DIMX;
    float4 v = *(const float4*)(xr + lane * 4);
    float s = v.x + v.y + v.z + v.w;
    float ss = v.x * v.x + v.y * v.y + v.z * v.z + v.w * v.w;
#pragma unroll
    for (int o = 32; o > 0; o >>= 1) { s += __shfl_xor(s, o); ss += __shfl_xor(ss, o); }
    const float mu = s * (1.0f / 256.0f);
    const float var = ss * (1.0f / 256.0f) - mu * mu;
    const float rstd = rsqrtf(var + 1e-5f);
    float vv[4] = {v.x, v.y, v.z, v.w};
#pragma unroll
    for (int q = 0; q < 4; ++q) {
      const int d = lane * 4 + q;
      float xn = (vv[q] - mu) * rstd * ln_g[d] + ln_b[d];
      g[r][d] = 0.5f * xn * (1.0f + erff(xn * 0.70710678118654752f));
    }
  }
  __syncthreads();
  float acc[16][4];
#pragma unroll
  for (int r = 0; r < 16; ++r)
#pragma unroll
    for (int c = 0; c < 4; ++c) acc[r][c] = 0.f;
#pragma unroll 4
  for (int d = 0; d < DIMX; ++d) {
    float4 w = *(const float4*)(w_pre + (size_t)d * CDIM + t * 4);
#pragma unroll
    for (int r = 0; r < 16; ++r) {
      const float gv = g[r][d];
      acc[r][0] = fmaf(gv, w.x, acc[r][0]);
      acc[r][1] = fmaf(gv, w.y, acc[r][1]);
      acc[r][2] = fmaf(gv, w.z, acc[r][2]);
      acc[r][3] = fmaf(gv, w.w, acc[r][3]);
    }
  }
  float4 bp = *(const float4*)(b_pre + t * 4);
  float ps[16];
#pragma unroll
  for (int r = 0; r < 16; ++r) {
    float4 o;
    o.x = acc[r][0] + bp.x; o.y = acc[r][1] + bp.y;
    o.z = acc[r][2] + bp.z; o.w = acc[r][3] + bp.w;
    unsigned short h0, l0, h1, l1, h2, l2, h3, l3;
    bf_split(o.x, h0, l0); bf_split(o.y, h1, l1);
    bf_split(o.z, h2, l2); bf_split(o.w, h3, l3);
    *(short4*)(zh + (size_t)(lrow0 + r) * CDIM + t * 4) =
        make_short4((short)h0, (short)h1, (short)h2, (short)h3);
    *(short4*)(zl + (size_t)(lrow0 + r) * CDIM + t * 4) =
        make_short4((short)l0, (short)l1, (short)l2, (short)l3);
    ps[r] = o.x * o.x + o.y * o.y + o.z * o.z + o.w * o.w;
  }
#pragma unroll
  for (int r = 0; r < 16; ++r)
#pragma unroll
    for (int o = 32; o > 0; o >>= 1) ps[r] += __shfl_xor(ps[r], o);
  __shared__ float zps[4][16];
  if (lane == 0)
#pragma unroll
    for (int r = 0; r < 16; ++r) zps[wv][r] = ps[r];
  __syncthreads();
  if (t < 16) z_sq[grow0 + t] = zps[0][t] + zps[1][t] + zps[2][t] + zps[3][t];
}

// ---------------- K2: coarse 1x bf16 MFMA scorer + candidate collect --------
// grid = (chunk/256)*NSP ; block = 512 (8 waves: 2M x 4N)
// LDS buffer (shorts): Eh frags [0..15]*512 | Zh frags +8192 ; dbuf 2x32KB
__global__ __launch_bounds__(512) void k_score(
    const short* __restrict__ Eh, const short* __restrict__ Zh,
    const float* __restrict__ e_sq, uint2* __restrict__ cand, int chunk) {
  __shared__ __align__(16) short lds[2][16384];
  const int t = threadIdx.x;
  const int cpx = gridDim.x >> 3;  // bijective XCD swizzle, grid % 8 == 0
  const int bx = (blockIdx.x & 7) * cpx + (blockIdx.x >> 3);
  const int zblk = bx / NSP, csp = bx % NSP;
  const int wid = t >> 6, l = t & 63;
  const int wr = wid >> 2, wc = wid & 3;
  const int lg = l >> 4, lo16 = l & 15;
  const int rowbase = zblk * 256;
  const int m0 = csp * 256;
  const int wr8 = wr * 8, wc4 = wc * 4, l8 = l * 8;

  // staging: waves 0-3 -> Eh quarters, waves 4-7 -> Zh quarters
  const bool isA = (wid < 4);
  const int q = wid & 3;
  const short* sarr = isA ? Eh : Zh;
  const int sbase = isA ? m0 : rowbase;
  const short* sp0 = sarr + (size_t)(sbase + q * 64 + lo16) * 1024 + lg * 8;
  const int dstbase = (isA ? 0 : 8192) + q * 4 * 512;

  f32x4 acc[8][4];
#pragma unroll
  for (int mi = 0; mi < 8; ++mi)
#pragma unroll
    for (int ni = 0; ni < 4; ++ni) acc[mi][ni] = (f32x4){0.f, 0.f, 0.f, 0.f};

  // prologue: stage kt=0
#pragma unroll
  for (int u = 0; u < 4; ++u)
    GLOAD_LDS16(sp0 + u * 16384, &lds[0][dstbase + u * 512]);
  asm volatile("s_waitcnt vmcnt(0)" ::: "memory");
  __builtin_amdgcn_s_barrier();
  __builtin_amdgcn_sched_barrier(0);

  for (int kt = 0; kt < 32; ++kt) {
    const int cur = kt & 1;
    const short* Lc = lds[cur];
    short* Dst = &lds[cur ^ 1][dstbase];
    const short* spk = sp0 + (kt + 1) * 32;
    const bool st = (kt < 31);

    bf16x8 bh[4];
#pragma unroll
    for (int ni = 0; ni < 4; ++ni)
      bh[ni] = *(const bf16x8*)(Lc + 8192 + (wc4 + ni) * 512 + l8);

#pragma unroll
    for (int p = 0; p < 2; ++p) {
      const int mi0 = 4 * p;
      bf16x8 a[4];
#pragma unroll
      for (int u = 0; u < 4; ++u)
        a[u] = *(const bf16x8*)(Lc + (wr8 + mi0 + u) * 512 + l8);
      if (p == 0 && st) {
#pragma unroll
        for (int u = 0; u < 4; ++u)
          GLOAD_LDS16(spk + u * 16384, Dst + u * 512);
      }
      __builtin_amdgcn_s_barrier();
      asm volatile("s_waitcnt lgkmcnt(0)" ::: "memory");
      __builtin_amdgcn_sched_barrier(0);
      __builtin_amdgcn_s_setprio(1);
#pragma unroll
      for (int u = 0; u < 4; ++u)
#pragma unroll
        for (int ni = 0; ni < 4; ++ni)
          acc[mi0 + u][ni] = __builtin_amdgcn_mfma_f32_16x16x32_bf16(
              a[u], bh[ni], acc[mi0 + u][ni], 0, 0, 0);
      __builtin_amdgcn_s_setprio(0);
      if (p == 1) asm volatile("s_waitcnt vmcnt(0)" ::: "memory");
      __builtin_amdgcn_s_barrier();
      __builtin_amdgcn_sched_barrier(0);
    }
  }

  // ---- epilogue: strip-min + candidate collect ----
  float s1[4];
  int i1[4];
#pragma unroll
  for (int i = 0; i < 4; ++i) { s1[i] = FLT_BIG; i1[i] = 0x7fffffff; }
#pragma unroll
  for (int mi = 0; mi < 8; ++mi) {
    const int c0 = m0 + wr * 128 + mi * 16 + lg * 4;
    float4 es = *(const float4*)(e_sq + c0);
    float esv[4] = {es.x, es.y, es.z, es.w};
#pragma unroll
    for (int ni = 0; ni < 4; ++ni) {
#pragma unroll
      for (int j = 0; j < 4; ++j) {
        const float s = fmaf(-2.0f, acc[mi][ni][j], esv[j]);
        const int c = c0 + j;
        if (s < s1[ni] || (s == s1[ni] && c < i1[ni])) { s1[ni] = s; i1[ni] = c; }
      }
    }
  }

  unsigned long long* red = (unsigned long long*)&lds[0][0];      // 512 u64
  float* sb = (float*)&lds[0][2048];                              // 256 f32
  unsigned* sbi = (unsigned*)&lds[0][2560];                       // 256 u32
  unsigned* cnt = (unsigned*)&lds[0][3072];                       // 256 u32
  uint2* slot = (uint2*)&lds[0][3584];                            // 256*3

#pragma unroll
  for (int ni = 0; ni < 4; ++ni) {
    unsigned long long k1v =
        (((unsigned long long)fkey(s1[ni])) << 32) | (unsigned)i1[ni];
    unsigned long long o1 = __shfl_xor(k1v, 16);
    k1v = o1 < k1v ? o1 : k1v;
    o1 = __shfl_xor(k1v, 32);
    k1v = o1 < k1v ? o1 : k1v;
    if (lg == 0) {
      const int r = wc * 64 + ni * 16 + lo16;
      red[r * 2 + wr] = k1v;
    }
  }
  __syncthreads();
  if (t < 256) {
    unsigned long long a1 = red[t * 2 + 0], b1 = red[t * 2 + 1];
    if (b1 < a1) a1 = b1;
    sb[t] = keyinv((unsigned)(a1 >> 32));
    sbi[t] = (unsigned)(a1 & 0xFFFFFFFFull);
    cnt[t] = 0;
  }
  __syncthreads();
  // candidate pass: emit codes within CMARG of strip-min (excluding the min)
#pragma unroll
  for (int mi = 0; mi < 8; ++mi) {
    const int c0 = m0 + wr * 128 + mi * 16 + lg * 4;
    float4 es = *(const float4*)(e_sq + c0);
    float esv[4] = {es.x, es.y, es.z, es.w};
#pragma unroll
    for (int ni = 0; ni < 4; ++ni) {
      const int r = wc * 64 + ni * 16 + lo16;
      const float thr = sb[r] + CMARG;
#pragma unroll
      for (int j = 0; j < 4; ++j) {
        const float s = fmaf(-2.0f, acc[mi][ni][j], esv[j]);
        const unsigned c = (unsigned)(c0 + j);
        if (s < thr && c != sbi[r]) {
          unsigned pos = atomicAdd(&cnt[r], 1u);
          if (pos < 3) slot[r * 3 + pos] = make_uint2(__float_as_uint(s), c);
        }
      }
    }
  }
  __syncthreads();
  if (t < 256) {
    uint2* g = cand + ((size_t)csp * chunk + rowbase + t) * 4;
    const unsigned ov = (cnt[t] > 3) ? 0x40000000u : 0u;
    g[0] = make_uint2(__float_as_uint(sb[t]), sbi[t] | ov);
    const unsigned n = cnt[t] > 3 ? 3 : cnt[t];
#pragma unroll
    for (int k = 0; k < 3; ++k)
      g[1 + k] = (k < (int)n) ? slot[t * 3 + k]
                              : make_uint2(__float_as_uint(FLT_BIG), 0xFFFFFFFFu);
  }
}

// ---------------- K3: refine candidates exactly (f64 on zh+zl) --------------
__global__ __launch_bounds__(256) void k_refine(
    const uint2* __restrict__ cand, const short* __restrict__ zh,
    const short* __restrict__ zl, const float* __restrict__ embed,
    int* __restrict__ idxf, float* __restrict__ crow,
    float* __restrict__ out_idx, int* __restrict__ flag_rows,
    int* __restrict__ nflag, int chunk, int row0) {
  const int t = threadIdx.x, wid = t >> 6, l = t & 63;
  for (int lrow = blockIdx.x * 4 + wid; lrow < chunk; lrow += gridDim.x * 4) {
    const int grow = row0 + lrow;
    // lane l -> strip l>>2, slot l&3
    const uint2 cs = cand[((size_t)(l >> 2) * chunk + lrow) * 4 + (l & 3)];
    const float sc = __uint_as_float(cs.x);
    const unsigned raw = cs.y;
    const bool isMin = (l & 3) == 0;
    float sm = isMin ? sc : FLT_BIG;
#pragma unroll
    for (int o = 32; o > 0; o >>= 1) sm = fminf(sm, __shfl_xor(sm, o));
    const bool ovf =
        __any(isMin && (raw & 0x40000000u) && sc < sm + CMARG);
    // z row in registers (f32 = hi+lo, exact sum)
    float zv[16];
#pragma unroll
    for (int j = 0; j < 16; ++j) {
      const int d = l + 64 * j;
      const int h = zh[(size_t)lrow * CDIM + d];
      const int lo = zl[(size_t)lrow * CDIM + d];
      zv[j] = __uint_as_float(((unsigned)(unsigned short)h) << 16) +
              __uint_as_float(((unsigned)(unsigned short)lo) << 16);
    }
    const bool valid = (raw != 0xFFFFFFFFu) && (sc < sm + CMARG);
    unsigned long long mask = __ballot(valid);
    double d1 = 1e300, d2 = 1e300;
    int i1 = 0x7fffffff, i2 = 0x7fffffff;
    const int myidx = (int)(raw & 0xFFFFu);
    while (mask) {
      const int src = __ffsll(mask) - 1;
      mask &= mask - 1;
      const int c = __shfl(myidx, src);
      const float* e = embed + (size_t)c * CDIM;
      double dd = 0.0;
#pragma unroll
      for (int j = 0; j < 16; ++j) {
        const double df = (double)zv[j] - (double)e[l + 64 * j];
        dd = fma(df, df, dd);
      }
#pragma unroll
      for (int o = 32; o > 0; o >>= 1) dd += __shfl_xor(dd, o);
      if (dd < d1 || (dd == d1 && c < i1)) {
        d2 = d1; i2 = i1; d1 = dd; i1 = c;
      } else if (dd < d2 || (dd == d2 && c < i2)) {
        d2 = dd; i2 = c;
      }
    }
    if (l == 0) {
      idxf[grow] = i1;
      out_idx[grow] = (float)i1;
      crow[grow] = (float)d1;
      if (ovf || (d2 - d1 < 0.03)) {
        const int s = atomicAdd(nflag, 1);
        flag_rows[s] = grow;
      }
    }
  }
}

// ---------------- K3b: exact f64 full rescan of flagged rows ----------------
__global__ __launch_bounds__(256) void k_exact(
    const float* __restrict__ x, const float* __restrict__ ln_g,
    const float* __restrict__ ln_b, const float* __restrict__ w_pre,
    const float* __restrict__ b_pre, const float* __restrict__ embed,
    const int* __restrict__ flag_rows, const int* __restrict__ nflag,
    int* __restrict__ idxf, float* __restrict__ crow,
    float* __restrict__ out_idx) {
  __shared__ float gsh[256];
  __shared__ float zrow[1024];
  __shared__ double wd[4];
  __shared__ int wcidx[4];
  const int t = threadIdx.x;
  const int wid = t >> 6, l = t & 63;
  const int n = *nflag;

  for (int fi = blockIdx.x; fi < n; fi += gridDim.x) {
    const int grow = flag_rows[fi];
    if (t < 64) {
      float4 v = *(const float4*)(x + (size_t)grow * DIMX + t * 4);
      float s = v.x + v.y + v.z + v.w;
      float ss = v.x * v.x + v.y * v.y + v.z * v.z + v.w * v.w;
#pragma unroll
      for (int o = 32; o > 0; o >>= 1) { s += __shfl_xor(s, o); ss += __shfl_xor(ss, o); }
      const float mu = s * (1.0f / 256.0f);
      const float var = ss * (1.0f / 256.0f) - mu * mu;
      const float rstd = rsqrtf(var + 1e-5f);
      float vv[4] = {v.x, v.y, v.z, v.w};
#pragma unroll
      for (int q = 0; q < 4; ++q) {
        const int d = t * 4 + q;
        float xn = (vv[q] - mu) * rstd * ln_g[d] + ln_b[d];
        gsh[d] = 0.5f * xn * (1.0f + erff(xn * 0.70710678118654752f));
      }
    }
    __syncthreads();
    float a0 = 0.f, a1f = 0.f, a2f = 0.f, a3f = 0.f;
    for (int d = 0; d < DIMX; ++d) {
      float4 w = *(const float4*)(w_pre + (size_t)d * CDIM + t * 4);
      const float gv = gsh[d];
      a0 = fmaf(gv, w.x, a0); a1f = fmaf(gv, w.y, a1f);
      a2f = fmaf(gv, w.z, a2f); a3f = fmaf(gv, w.w, a3f);
    }
    float4 bp = *(const float4*)(b_pre + t * 4);
    zrow[t * 4 + 0] = a0 + bp.x; zrow[t * 4 + 1] = a1f + bp.y;
    zrow[t * 4 + 2] = a2f + bp.z; zrow[t * 4 + 3] = a3f + bp.w;
    __syncthreads();
    float zr[16];
#pragma unroll
    for (int j = 0; j < 16; ++j) zr[j] = zrow[l + 64 * j];
    double dmin = 1e300;
    int cmin = 0x7fffffff;
    for (int ci = 0; ci < 1024; ++ci) {
      const int c = wid * 1024 + ci;
      const float* e = embed + (size_t)c * CDIM;
      double dd = 0.0;
#pragma unroll
      for (int j = 0; j < 16; ++j) {
        const double df = (double)zr[j] - (double)e[l + 64 * j];
        dd = fma(df, df, dd);
      }
#pragma unroll
      for (int o = 32; o > 0; o >>= 1) dd += __shfl_xor(dd, o);
      if (dd < dmin) { dmin = dd; cmin = c; }
    }
    if (l == 0) { wd[wid] = dmin; wcidx[wid] = cmin; }
    __syncthreads();
    if (t == 0) {
      double dm = wd[0]; int cm = wcidx[0];
#pragma unroll
      for (int wv = 1; wv < 4; ++wv) {
        if (wd[wv] < dm || (wd[wv] == dm && wcidx[wv] < cm)) {
          dm = wd[wv]; cm = wcidx[wv];
        }
      }
      idxf[grow] = cm;
      out_idx[grow] = (float)cm;
      crow[grow] = (float)dm;
    }
    __syncthreads();
  }
}

// ---------------- K4: E_post = embed @ w_post ----------------
__global__ __launch_bounds__(256) void k_epost(const float* __restrict__ E,
                                               const float* __restrict__ w_post,
                                               float* __restrict__ E_post) {
  __shared__ float es[16][128];
  const int t = threadIdx.x;
  const int r0 = blockIdx.x * 16;
  float acc[16];
#pragma unroll
  for (int r = 0; r < 16; ++r) acc[r] = 0.f;
  for (int k0 = 0; k0 < CDIM; k0 += 128) {
    __syncthreads();
#pragma unroll
    for (int p = 0; p < 2; ++p) {
      const int fl = (p * 256 + t) * 4;
      const int r = fl >> 7, kk = fl & 127;
      float4 v = *(const float4*)(E + (size_t)(r0 + r) * CDIM + k0 + kk);
      *(float4*)&es[r][kk] = v;
    }
    __syncthreads();
#pragma unroll 4
    for (int d = 0; d < 128; ++d) {
      const float w = w_post[(size_t)(k0 + d) * DIMX + t];
#pragma unroll
      for (int r = 0; r < 16; ++r) acc[r] = fmaf(es[r][d], w, acc[r]);
    }
  }
#pragma unroll
  for (int r = 0; r < 16; ++r)
    E_post[(size_t)(r0 + r) * DIMX + t] = acc[r];
}

// ---------------- K5: gather E_post rows + bias ----------------
__global__ __launch_bounds__(256) void k_gather(const float* __restrict__ E_post,
                                                const int* __restrict__ idx,
                                                const float* __restrict__ b_post,
                                                float* __restrict__ outq) {
  const int t = threadIdx.x;
  const int r0 = blockIdx.x * 16;
  const float bp = b_post[t];
#pragma unroll
  for (int i = 0; i < 16; ++i) {
    const int row = r0 + i;
    outq[(size_t)row * DIMX + t] = E_post[(size_t)idx[row] * DIMX + t] + bp;
  }
}

// ---------------- K6: commit reduce ----------------
__global__ __launch_bounds__(256) void k_commit_final(
    const float* __restrict__ crow, float* __restrict__ out_commit) {
  const int t = threadIdx.x;
  double s = 0.0;
  for (int i = t; i < BN_ROWS; i += 256) s += (double)crow[i];
#pragma unroll
  for (int o = 32; o > 0; o >>= 1) s += __shfl_xor(s, o);
  __shared__ double wsum[4];
  if ((t & 63) == 0) wsum[t >> 6] = s;
  __syncthreads();
  if (t == 0)
    *out_commit = (float)(0.25 * (wsum[0] + wsum[1] + wsum[2] + wsum[3]) /
                          (65536.0 * 1024.0));
}

extern "C" void kernel_launch(void* const* d_in, const int* in_sizes, int n_in,
                              void* d_out, int out_size, void* d_ws,
                              size_t ws_size, hipStream_t stream) {
  const float* x = (const float*)d_in[0];
  const float* ln_g = (const float*)d_in[1];
  const float* ln_b = (const float*)d_in[2];
  const float* w_pre = (const float*)d_in[3];
  const float* b_pre = (const float*)d_in[4];
  const float* embed = (const float*)d_in[5];
  const float* w_post = (const float*)d_in[6];
  const float* b_post = (const float*)d_in[7];

  float* out = (float*)d_out;
  float* outq = out;                   // 16777216 f32
  float* out_idx = out + 16777216;     // 65536 f32
  float* out_commit = out + 16842752;  // 1 f32

  char* ws = (char*)d_ws;
  float* e_sq = (float*)(ws + OFF_ESQ);
  float* z_sq = (float*)(ws + OFF_ZSQ);
  int* idxf = (int*)(ws + OFF_IDXF);
  float* crow = (float*)(ws + OFF_CROW);
  float* E_post = (float*)(ws + OFF_EPOST);
  short* Eh = (short*)(ws + OFF_EH);
  int* nflag = (int*)(ws + OFF_NFLAG);
  int* flag_rows = (int*)(ws + OFF_FLAG);

  // chunk rows sized to ws: per-row = 512B (cand) + 4096B (zh+zl)
  int chunk = 4096;
  while (chunk < BN_ROWS &&
         OFF_CAND + (size_t)(chunk * 2) * 4608ull <= ws_size)
    chunk *= 2;
  uint2* cand = (uint2*)(ws + OFF_CAND);
  short* zh = (short*)(ws + OFF_CAND + (size_t)chunk * 512);
  short* zl = (short*)(ws + OFF_CAND + (size_t)chunk * 512 + (size_t)chunk * 2048);

  hipMemsetAsync(nflag, 0, sizeof(int), stream);
  k_esq<<<KCODES / 4, 256, 0, stream>>>(embed, e_sq);
  k_ehi<<<KCODES, 256, 0, stream>>>(embed, Eh);
  k_epost<<<KCODES / 16, 256, 0, stream>>>(embed, w_post, E_post);

  for (int row0 = 0; row0 < BN_ROWS; row0 += chunk) {
    k_ln_gelu_gemm<<<chunk / 16, 256, 0, stream>>>(x, ln_g, ln_b, w_pre, b_pre,
                                                   zh, zl, z_sq, row0);
    k_score<<<(chunk / 256) * NSP, 512, 0, stream>>>(Eh, zh, e_sq, cand, chunk);
    k_refine<<<2048, 256, 0, stream>>>(cand, zh, zl, embed, idxf, crow,
                                       out_idx, flag_rows, nflag, chunk, row0);
  }

  k_exact<<<1024, 256, 0, stream>>>(x, ln_g, ln_b, w_pre, b_pre, embed,
                                    flag_rows, nflag, idxf, crow, out_idx);
  k_gather<<<BN_ROWS / 16, 256, 0, stream>>>(E_post, idxf, b_post, outq);
  k_commit_final<<<1, 256, 0, stream>>>(crow, out_commit);
}

// Round 8
// 1585.224 us; speedup vs baseline: 6.8892x; 1.5089x over previous
//
#include <hip/hip_runtime.h>

#define BN_ROWS 65536
#define DIMX 256
#define CDIM 1024
#define KCODES 4096
#define NSP 16          // code strips of 256
#define CMARG 2.5f      // coarse capture margin within a strip
#define RMARG 1.2f      // refine filter margin above global coarse min
#define FLT_BIG 3.402823466e+38f

// ---------------- ws layout (bytes) ----------------
static const size_t OFF_ESQ   = 0;          // 4096 f32 (16KB)
static const size_t OFF_IDXF  = 16384;      // 65536 i32
static const size_t OFF_CROW  = 278528;     // 65536 f32
static const size_t OFF_EPOST = 540672;     // 4096*256 f32 (4MB)
static const size_t OFF_EH    = 4734976;    // 4096*1024 bf16 (8MB)
static const size_t OFF_NFLAG = 13123584;   // 1 i32 (+pad)
static const size_t OFF_FLAG  = 13123648;   // 65536 i32
static const size_t OFF_CAND  = 13385792;   // chunk * 64 entries * 8B (row-major)
// zh = OFF_CAND + chunk*512 ; zf = zh + chunk*2048 (fp32 z, 4KB/row)

typedef __attribute__((ext_vector_type(8))) short bf16x8;
typedef __attribute__((ext_vector_type(4))) float f32x4;

#define GLOAD_LDS16(gsrc, ldst)                                                \
  __builtin_amdgcn_global_load_lds(                                            \
      (const __attribute__((address_space(1))) void*)(gsrc),                   \
      (__attribute__((address_space(3))) void*)(ldst), 16, 0, 0)

__device__ inline unsigned short bf_rtn(float f) {
  unsigned u = __float_as_uint(f);
  unsigned r = (u + 0x7FFFu + ((u >> 16) & 1u)) >> 16;
  return (unsigned short)r;
}
__device__ inline unsigned fkey(float s) {
  unsigned b = __float_as_uint(s);
  return b ^ ((unsigned)((int)b >> 31) | 0x80000000u);
}
__device__ inline float keyinv(unsigned k) {
  unsigned b = (k & 0x80000000u) ? (k ^ 0x80000000u) : ~k;
  return __uint_as_float(b);
}

// ---------------- K0: e_sq ----------------
__global__ __launch_bounds__(256) void k_esq(const float* __restrict__ embed,
                                             float* __restrict__ e_sq) {
  const int t = threadIdx.x, wv = t >> 6, lane = t & 63;
  const int row = blockIdx.x * 4 + wv;
  const float* e = embed + (size_t)row * CDIM;
  float s = 0.f;
  for (int k = lane * 4; k < CDIM; k += 256) {
    float4 v = *(const float4*)(e + k);
    s = fmaf(v.x, v.x, s); s = fmaf(v.y, v.y, s);
    s = fmaf(v.z, v.z, s); s = fmaf(v.w, v.w, s);
  }
#pragma unroll
  for (int o = 32; o > 0; o >>= 1) s += __shfl_xor(s, o);
  if (lane == 0) e_sq[row] = s;
}

// ---------------- K0b: E -> hi bf16 ----------------
__global__ __launch_bounds__(256) void k_ehi(const float* __restrict__ embed,
                                             short* __restrict__ Eh) {
  const int t = threadIdx.x;
  const size_t row = blockIdx.x;
  float4 v = *(const float4*)(embed + row * CDIM + t * 4);
  *(short4*)(Eh + row * CDIM + t * 4) =
      make_short4((short)bf_rtn(v.x), (short)bf_rtn(v.y), (short)bf_rtn(v.z),
                  (short)bf_rtn(v.w));
}

// ---------------- K1: LN + GELU + @w_pre -> z fp32 + z bf16-hi ----------------
__global__ __launch_bounds__(256) void k_ln_gelu_gemm(
    const float* __restrict__ x, const float* __restrict__ ln_g,
    const float* __restrict__ ln_b, const float* __restrict__ w_pre,
    const float* __restrict__ b_pre, float* __restrict__ zf,
    short* __restrict__ zh, int row0) {
  __shared__ float g[16][DIMX];
  const int t = threadIdx.x;
  const int lrow0 = blockIdx.x * 16;
  const int grow0 = row0 + lrow0;
  const int wv = t >> 6, lane = t & 63;
#pragma unroll
  for (int j = 0; j < 4; ++j) {
    const int r = wv * 4 + j;
    const float* xr = x + (size_t)(grow0 + r) * DIMX;
    float4 v = *(const float4*)(xr + lane * 4);
    float s = v.x + v.y + v.z + v.w;
    float ss = v.x * v.x + v.y * v.y + v.z * v.z + v.w * v.w;
#pragma unroll
    for (int o = 32; o > 0; o >>= 1) { s += __shfl_xor(s, o); ss += __shfl_xor(ss, o); }
    const float mu = s * (1.0f / 256.0f);
    const float var = ss * (1.0f / 256.0f) - mu * mu;
    const float rstd = rsqrtf(var + 1e-5f);
    float vv[4] = {v.x, v.y, v.z, v.w};
#pragma unroll
    for (int q = 0; q < 4; ++q) {
      const int d = lane * 4 + q;
      float xn = (vv[q] - mu) * rstd * ln_g[d] + ln_b[d];
      g[r][d] = 0.5f * xn * (1.0f + erff(xn * 0.70710678118654752f));
    }
  }
  __syncthreads();
  float acc[16][4];
#pragma unroll
  for (int r = 0; r < 16; ++r)
#pragma unroll
    for (int c = 0; c < 4; ++c) acc[r][c] = 0.f;
#pragma unroll 4
  for (int d = 0; d < DIMX; ++d) {
    float4 w = *(const float4*)(w_pre + (size_t)d * CDIM + t * 4);
#pragma unroll
    for (int r = 0; r < 16; ++r) {
      const float gv = g[r][d];
      acc[r][0] = fmaf(gv, w.x, acc[r][0]);
      acc[r][1] = fmaf(gv, w.y, acc[r][1]);
      acc[r][2] = fmaf(gv, w.z, acc[r][2]);
      acc[r][3] = fmaf(gv, w.w, acc[r][3]);
    }
  }
  float4 bp = *(const float4*)(b_pre + t * 4);
#pragma unroll
  for (int r = 0; r < 16; ++r) {
    float4 o;
    o.x = acc[r][0] + bp.x; o.y = acc[r][1] + bp.y;
    o.z = acc[r][2] + bp.z; o.w = acc[r][3] + bp.w;
    *(float4*)(zf + (size_t)(lrow0 + r) * CDIM + t * 4) = o;
    *(short4*)(zh + (size_t)(lrow0 + r) * CDIM + t * 4) =
        make_short4((short)bf_rtn(o.x), (short)bf_rtn(o.y), (short)bf_rtn(o.z),
                    (short)bf_rtn(o.w));
  }
}

// ---------------- K2: coarse 1x bf16 MFMA scorer + candidate collect --------
// grid = (chunk/256)*NSP ; block = 512 (8 waves: 2M x 4N)
__global__ __launch_bounds__(512) void k_score(
    const short* __restrict__ Eh, const short* __restrict__ Zh,
    const float* __restrict__ e_sq, uint2* __restrict__ cand, int chunk) {
  __shared__ __align__(16) short lds[2][16384];
  const int t = threadIdx.x;
  const int cpx = gridDim.x >> 3;  // bijective XCD swizzle, grid % 8 == 0
  const int bx = (blockIdx.x & 7) * cpx + (blockIdx.x >> 3);
  const int zblk = bx / NSP, csp = bx % NSP;
  const int wid = t >> 6, l = t & 63;
  const int wr = wid >> 2, wc = wid & 3;
  const int lg = l >> 4, lo16 = l & 15;
  const int rowbase = zblk * 256;
  const int m0 = csp * 256;
  const int wr8 = wr * 8, wc4 = wc * 4, l8 = l * 8;

  const bool isA = (wid < 4);
  const int q = wid & 3;
  const short* sarr = isA ? Eh : Zh;
  const int sbase = isA ? m0 : rowbase;
  const short* sp0 = sarr + (size_t)(sbase + q * 64 + lo16) * 1024 + lg * 8;
  const int dstbase = (isA ? 0 : 8192) + q * 4 * 512;

  f32x4 acc[8][4];
#pragma unroll
  for (int mi = 0; mi < 8; ++mi)
#pragma unroll
    for (int ni = 0; ni < 4; ++ni) acc[mi][ni] = (f32x4){0.f, 0.f, 0.f, 0.f};

#pragma unroll
  for (int u = 0; u < 4; ++u)
    GLOAD_LDS16(sp0 + u * 16384, &lds[0][dstbase + u * 512]);
  asm volatile("s_waitcnt vmcnt(0)" ::: "memory");
  __builtin_amdgcn_s_barrier();
  __builtin_amdgcn_sched_barrier(0);

  for (int kt = 0; kt < 32; ++kt) {
    const int cur = kt & 1;
    const short* Lc = lds[cur];
    short* Dst = &lds[cur ^ 1][dstbase];
    const short* spk = sp0 + (kt + 1) * 32;
    const bool st = (kt < 31);

    bf16x8 bh[4];
#pragma unroll
    for (int ni = 0; ni < 4; ++ni)
      bh[ni] = *(const bf16x8*)(Lc + 8192 + (wc4 + ni) * 512 + l8);

#pragma unroll
    for (int p = 0; p < 2; ++p) {
      const int mi0 = 4 * p;
      bf16x8 a[4];
#pragma unroll
      for (int u = 0; u < 4; ++u)
        a[u] = *(const bf16x8*)(Lc + (wr8 + mi0 + u) * 512 + l8);
      if (p == 0 && st) {
#pragma unroll
        for (int u = 0; u < 4; ++u)
          GLOAD_LDS16(spk + u * 16384, Dst + u * 512);
      }
      __builtin_amdgcn_s_barrier();
      asm volatile("s_waitcnt lgkmcnt(0)" ::: "memory");
      __builtin_amdgcn_sched_barrier(0);
      __builtin_amdgcn_s_setprio(1);
#pragma unroll
      for (int u = 0; u < 4; ++u)
#pragma unroll
        for (int ni = 0; ni < 4; ++ni)
          acc[mi0 + u][ni] = __builtin_amdgcn_mfma_f32_16x16x32_bf16(
              a[u], bh[ni], acc[mi0 + u][ni], 0, 0, 0);
      __builtin_amdgcn_s_setprio(0);
      if (p == 1) asm volatile("s_waitcnt vmcnt(0)" ::: "memory");
      __builtin_amdgcn_s_barrier();
      __builtin_amdgcn_sched_barrier(0);
    }
  }

  // ---- epilogue: strip-min + candidate collect ----
  float s1[4];
  int i1[4];
#pragma unroll
  for (int i = 0; i < 4; ++i) { s1[i] = FLT_BIG; i1[i] = 0x7fffffff; }
#pragma unroll
  for (int mi = 0; mi < 8; ++mi) {
    const int c0 = m0 + wr * 128 + mi * 16 + lg * 4;
    float4 es = *(const float4*)(e_sq + c0);
    float esv[4] = {es.x, es.y, es.z, es.w};
#pragma unroll
    for (int ni = 0; ni < 4; ++ni) {
#pragma unroll
      for (int j = 0; j < 4; ++j) {
        const float s = fmaf(-2.0f, acc[mi][ni][j], esv[j]);
        const int c = c0 + j;
        if (s < s1[ni] || (s == s1[ni] && c < i1[ni])) { s1[ni] = s; i1[ni] = c; }
      }
    }
  }

  unsigned long long* red = (unsigned long long*)&lds[0][0];      // 512 u64
  float* sb = (float*)&lds[0][2048];                              // 256 f32
  unsigned* sbi = (unsigned*)&lds[0][2560];                       // 256 u32
  unsigned* cnt = (unsigned*)&lds[0][3072];                       // 256 u32
  uint2* slot = (uint2*)&lds[0][3584];                            // 256*3

#pragma unroll
  for (int ni = 0; ni < 4; ++ni) {
    unsigned long long k1v =
        (((unsigned long long)fkey(s1[ni])) << 32) | (unsigned)i1[ni];
    unsigned long long o1 = __shfl_xor(k1v, 16);
    k1v = o1 < k1v ? o1 : k1v;
    o1 = __shfl_xor(k1v, 32);
    k1v = o1 < k1v ? o1 : k1v;
    if (lg == 0) {
      const int r = wc * 64 + ni * 16 + lo16;
      red[r * 2 + wr] = k1v;
    }
  }
  __syncthreads();
  if (t < 256) {
    unsigned long long a1 = red[t * 2 + 0], b1 = red[t * 2 + 1];
    if (b1 < a1) a1 = b1;
    sb[t] = keyinv((unsigned)(a1 >> 32));
    sbi[t] = (unsigned)(a1 & 0xFFFFFFFFull);
    cnt[t] = 0;
  }
  __syncthreads();
#pragma unroll
  for (int mi = 0; mi < 8; ++mi) {
    const int c0 = m0 + wr * 128 + mi * 16 + lg * 4;
    float4 es = *(const float4*)(e_sq + c0);
    float esv[4] = {es.x, es.y, es.z, es.w};
#pragma unroll
    for (int ni = 0; ni < 4; ++ni) {
      const int r = wc * 64 + ni * 16 + lo16;
      const float thr = sb[r] + CMARG;
#pragma unroll
      for (int j = 0; j < 4; ++j) {
        const float s = fmaf(-2.0f, acc[mi][ni][j], esv[j]);
        const unsigned c = (unsigned)(c0 + j);
        if (s < thr && c != sbi[r]) {
          unsigned pos = atomicAdd(&cnt[r], 1u);
          if (pos < 3) slot[r * 3 + pos] = make_uint2(__float_as_uint(s), c);
        }
      }
    }
  }
  __syncthreads();
  if (t < 256) {
    // row-major: 64 contiguous entries per row (16 strips x 4 slots)
    uint2* g = cand + ((size_t)(rowbase + t) * NSP + csp) * 4;
    const unsigned ov = (cnt[t] > 3) ? 0x40000000u : 0u;
    g[0] = make_uint2(__float_as_uint(sb[t]), sbi[t] | ov);
    const unsigned n = cnt[t] > 3 ? 3 : cnt[t];
#pragma unroll
    for (int k = 0; k < 3; ++k)
      g[1 + k] = (k < (int)n) ? slot[t * 3 + k]
                              : make_uint2(__float_as_uint(FLT_BIG), 0xFFFFFFFFu);
  }
}

// ---------------- K3: exact f64 refine on fp32 z over candidates ------------
__global__ __launch_bounds__(256) void k_refine(
    const uint2* __restrict__ cand, const float* __restrict__ zf,
    const float* __restrict__ embed, int* __restrict__ idxf,
    float* __restrict__ crow, float* __restrict__ out_idx,
    int* __restrict__ flag_rows, int* __restrict__ nflag, int chunk,
    int row0) {
  const int t = threadIdx.x, wid = t >> 6, l = t & 63;
  const int lrow = blockIdx.x * 4 + wid;
  if (lrow >= chunk) return;
  const int grow = row0 + lrow;
  // lane l holds candidate entry l (strip l>>2, slot l&3), 512B contiguous
  const uint2 cs = cand[(size_t)lrow * 64 + l];
  const float sc = __uint_as_float(cs.x);
  const unsigned raw = cs.y;
  const bool isMin = (l & 3) == 0;
  float gm = isMin ? sc : FLT_BIG;
#pragma unroll
  for (int o = 32; o > 0; o >>= 1) gm = fminf(gm, __shfl_xor(gm, o));
  const float thr = gm + RMARG;
  const bool ovf = __any(isMin && (raw & 0x40000000u) && (sc < thr));

  float zv[16];
#pragma unroll
  for (int j = 0; j < 16; ++j) zv[j] = zf[(size_t)lrow * CDIM + l + 64 * j];

  const int myidx = (int)(raw & 0xFFFFu);
  const bool valid = (sc < thr) && (myidx < KCODES);
  unsigned long long mask = __ballot(valid);
  double d1 = 1e300;
  int i1 = 0x7fffffff;
  while (mask) {
    const int src = __ffsll((unsigned long long)mask) - 1;
    mask &= mask - 1;
    const int c = __shfl(myidx, src);
    const float* e = embed + (size_t)c * CDIM;
    double dd = 0.0;
#pragma unroll
    for (int j = 0; j < 16; ++j) {
      const double df = (double)zv[j] - (double)e[l + 64 * j];
      dd = fma(df, df, dd);
    }
#pragma unroll
    for (int o = 32; o > 0; o >>= 1) dd += __shfl_xor(dd, o);
    if (dd < d1 || (dd == d1 && c < i1)) { d1 = dd; i1 = c; }
  }
  if (l == 0) {
    idxf[grow] = i1;
    out_idx[grow] = (float)i1;
    crow[grow] = (float)d1;
    if (ovf) {
      const int s = atomicAdd(nflag, 1);
      flag_rows[s] = lrow;
    }
  }
}

// ---------------- K3b: exact f64 full rescan (overflow rows only) -----------
__global__ __launch_bounds__(256) void k_exact(
    const float* __restrict__ zf, const float* __restrict__ embed,
    const int* __restrict__ flag_rows, const int* __restrict__ nflag,
    int* __restrict__ idxf, float* __restrict__ crow,
    float* __restrict__ out_idx, int row0) {
  __shared__ double wd[4];
  __shared__ int wcidx[4];
  const int t = threadIdx.x;
  const int wid = t >> 6, l = t & 63;
  const int n = *nflag;

  for (int fi = blockIdx.x; fi < n; fi += gridDim.x) {
    const int lrow = flag_rows[fi];
    const int grow = row0 + lrow;
    float zr[16];
#pragma unroll
    for (int j = 0; j < 16; ++j) zr[j] = zf[(size_t)lrow * CDIM + l + 64 * j];
    double dmin = 1e300;
    int cmin = 0x7fffffff;
    for (int ci = 0; ci < 1024; ++ci) {
      const int c = wid * 1024 + ci;
      const float* e = embed + (size_t)c * CDIM;
      double dd = 0.0;
#pragma unroll
      for (int j = 0; j < 16; ++j) {
        const double df = (double)zr[j] - (double)e[l + 64 * j];
        dd = fma(df, df, dd);
      }
#pragma unroll
      for (int o = 32; o > 0; o >>= 1) dd += __shfl_xor(dd, o);
      if (dd < dmin) { dmin = dd; cmin = c; }
    }
    if (l == 0) { wd[wid] = dmin; wcidx[wid] = cmin; }
    __syncthreads();
    if (t == 0) {
      double dm = wd[0]; int cm = wcidx[0];
#pragma unroll
      for (int wv = 1; wv < 4; ++wv) {
        if (wd[wv] < dm || (wd[wv] == dm && wcidx[wv] < cm)) {
          dm = wd[wv]; cm = wcidx[wv];
        }
      }
      idxf[grow] = cm;
      out_idx[grow] = (float)cm;
      crow[grow] = (float)dm;
    }
    __syncthreads();
  }
}

// ---------------- K4: E_post = embed @ w_post ----------------
__global__ __launch_bounds__(256) void k_epost(const float* __restrict__ E,
                                               const float* __restrict__ w_post,
                                               float* __restrict__ E_post) {
  __shared__ float es[16][128];
  const int t = threadIdx.x;
  const int r0 = blockIdx.x * 16;
  float acc[16];
#pragma unroll
  for (int r = 0; r < 16; ++r) acc[r] = 0.f;
  for (int k0 = 0; k0 < CDIM; k0 += 128) {
    __syncthreads();
#pragma unroll
    for (int p = 0; p < 2; ++p) {
      const int fl = (p * 256 + t) * 4;
      const int r = fl >> 7, kk = fl & 127;
      float4 v = *(const float4*)(E + (size_t)(r0 + r) * CDIM + k0 + kk);
      *(float4*)&es[r][kk] = v;
    }
    __syncthreads();
#pragma unroll 4
    for (int d = 0; d < 128; ++d) {
      const float w = w_post[(size_t)(k0 + d) * DIMX + t];
#pragma unroll
      for (int r = 0; r < 16; ++r) acc[r] = fmaf(es[r][d], w, acc[r]);
    }
  }
#pragma unroll
  for (int r = 0; r < 16; ++r)
    E_post[(size_t)(r0 + r) * DIMX + t] = acc[r];
}

// ---------------- K5: gather E_post rows + bias ----------------
__global__ __launch_bounds__(256) void k_gather(const float* __restrict__ E_post,
                                                const int* __restrict__ idx,
                                                const float* __restrict__ b_post,
                                                float* __restrict__ outq) {
  const int t = threadIdx.x;
  const int r0 = blockIdx.x * 16;
  const float bp = b_post[t];
#pragma unroll
  for (int i = 0; i < 16; ++i) {
    const int row = r0 + i;
    outq[(size_t)row * DIMX + t] = E_post[(size_t)idx[row] * DIMX + t] + bp;
  }
}

// ---------------- K6: commit reduce ----------------
__global__ __launch_bounds__(256) void k_commit_final(
    const float* __restrict__ crow, float* __restrict__ out_commit) {
  const int t = threadIdx.x;
  double s = 0.0;
  for (int i = t; i < BN_ROWS; i += 256) s += (double)crow[i];
#pragma unroll
  for (int o = 32; o > 0; o >>= 1) s += __shfl_xor(s, o);
  __shared__ double wsum[4];
  if ((t & 63) == 0) wsum[t >> 6] = s;
  __syncthreads();
  if (t == 0)
    *out_commit = (float)(0.25 * (wsum[0] + wsum[1] + wsum[2] + wsum[3]) /
                          (65536.0 * 1024.0));
}

extern "C" void kernel_launch(void* const* d_in, const int* in_sizes, int n_in,
                              void* d_out, int out_size, void* d_ws,
                              size_t ws_size, hipStream_t stream) {
  const float* x = (const float*)d_in[0];
  const float* ln_g = (const float*)d_in[1];
  const float* ln_b = (const float*)d_in[2];
  const float* w_pre = (const float*)d_in[3];
  const float* b_pre = (const float*)d_in[4];
  const float* embed = (const float*)d_in[5];
  const float* w_post = (const float*)d_in[6];
  const float* b_post = (const float*)d_in[7];

  float* out = (float*)d_out;
  float* outq = out;                   // 16777216 f32
  float* out_idx = out + 16777216;     // 65536 f32
  float* out_commit = out + 16842752;  // 1 f32

  char* ws = (char*)d_ws;
  float* e_sq = (float*)(ws + OFF_ESQ);
  int* idxf = (int*)(ws + OFF_IDXF);
  float* crow = (float*)(ws + OFF_CROW);
  float* E_post = (float*)(ws + OFF_EPOST);
  short* Eh = (short*)(ws + OFF_EH);
  int* nflag = (int*)(ws + OFF_NFLAG);
  int* flag_rows = (int*)(ws + OFF_FLAG);

  // chunk rows sized to ws: per-row = 512B (cand) + 2048B (zh) + 4096B (zf)
  int chunk = 4096;
  while (chunk < BN_ROWS &&
         OFF_CAND + (size_t)(chunk * 2) * 6656ull <= ws_size)
    chunk *= 2;
  uint2* cand = (uint2*)(ws + OFF_CAND);
  short* zh = (short*)(ws + OFF_CAND + (size_t)chunk * 512);
  float* zf = (float*)(ws + OFF_CAND + (size_t)chunk * 512 + (size_t)chunk * 2048);

  k_esq<<<KCODES / 4, 256, 0, stream>>>(embed, e_sq);
  k_ehi<<<KCODES, 256, 0, stream>>>(embed, Eh);
  k_epost<<<KCODES / 16, 256, 0, stream>>>(embed, w_post, E_post);

  for (int row0 = 0; row0 < BN_ROWS; row0 += chunk) {
    hipMemsetAsync(nflag, 0, sizeof(int), stream);
    k_ln_gelu_gemm<<<chunk / 16, 256, 0, stream>>>(x, ln_g, ln_b, w_pre, b_pre,
                                                   zf, zh, row0);
    k_score<<<(chunk / 256) * NSP, 512, 0, stream>>>(Eh, zh, e_sq, cand, chunk);
    k_refine<<<chunk / 4, 256, 0, stream>>>(cand, zf, embed, idxf, crow,
                                            out_idx, flag_rows, nflag, chunk,
                                            row0);
    k_exact<<<128, 256, 0, stream>>>(zf, embed, flag_rows, nflag, idxf, crow,
                                     out_idx, row0);
  }

  k_gather<<<BN_ROWS / 16, 256, 0, stream>>>(E_post, idxf, b_post, outq);
  k_commit_final<<<1, 256, 0, stream>>>(crow, out_commit);
}

// Round 9
// 1455.770 us; speedup vs baseline: 7.5018x; 1.0889x over previous
//
#include <hip/hip_runtime.h>

#define BN_ROWS 65536
#define DIMX 256
#define CDIM 1024
#define KCODES 4096
#define NSP 16          // code strips of 256
#define CMARG 2.5f      // coarse capture margin within a strip
#define RMARG 1.2f      // refine filter margin above global coarse min
#define FLT_BIG 3.402823466e+38f

// ---------------- ws layout (bytes) ----------------
static const size_t OFF_ESQ   = 0;          // 4096 f32 (16KB)
static const size_t OFF_IDXF  = 16384;      // 65536 i32
static const size_t OFF_CROW  = 278528;     // 65536 f32
static const size_t OFF_EPOST = 540672;     // 4096*256 f32 (4MB)
static const size_t OFF_EH    = 4734976;    // 4096*1024 bf16 (8MB)
static const size_t OFF_NFLAG = 13123584;   // 1 i32 (+pad)
static const size_t OFF_FLAG  = 13123648;   // 65536 i32
static const size_t OFF_CAND  = 13385792;   // chunk * 64 entries * 8B (row-major)
// zh = OFF_CAND + chunk*512 ; zf = zh + chunk*2048 (fp32 z, 4KB/row)

typedef __attribute__((ext_vector_type(8))) short bf16x8;
typedef __attribute__((ext_vector_type(4))) float f32x4;

#define GLOAD_LDS16(gsrc, ldst)                                                \
  __builtin_amdgcn_global_load_lds(                                            \
      (const __attribute__((address_space(1))) void*)(gsrc),                   \
      (__attribute__((address_space(3))) void*)(ldst), 16, 0, 0)

template <int VMC>
__device__ __forceinline__ void wait_vm() {
  if constexpr (VMC == 8)
    asm volatile("s_waitcnt vmcnt(8)" ::: "memory");
  else if constexpr (VMC == 4)
    asm volatile("s_waitcnt vmcnt(4)" ::: "memory");
  else
    asm volatile("s_waitcnt vmcnt(0)" ::: "memory");
}

__device__ inline unsigned short bf_rtn(float f) {
  unsigned u = __float_as_uint(f);
  unsigned r = (u + 0x7FFFu + ((u >> 16) & 1u)) >> 16;
  return (unsigned short)r;
}
__device__ inline unsigned fkey(float s) {
  unsigned b = __float_as_uint(s);
  return b ^ ((unsigned)((int)b >> 31) | 0x80000000u);
}
__device__ inline float keyinv(unsigned k) {
  unsigned b = (k & 0x80000000u) ? (k ^ 0x80000000u) : ~k;
  return __uint_as_float(b);
}

// ---------------- K0: e_sq ----------------
__global__ __launch_bounds__(256) void k_esq(const float* __restrict__ embed,
                                             float* __restrict__ e_sq) {
  const int t = threadIdx.x, wv = t >> 6, lane = t & 63;
  const int row = blockIdx.x * 4 + wv;
  const float* e = embed + (size_t)row * CDIM;
  float s = 0.f;
  for (int k = lane * 4; k < CDIM; k += 256) {
    float4 v = *(const float4*)(e + k);
    s = fmaf(v.x, v.x, s); s = fmaf(v.y, v.y, s);
    s = fmaf(v.z, v.z, s); s = fmaf(v.w, v.w, s);
  }
#pragma unroll
  for (int o = 32; o > 0; o >>= 1) s += __shfl_xor(s, o);
  if (lane == 0) e_sq[row] = s;
}

// ---------------- K0b: E -> hi bf16 ----------------
__global__ __launch_bounds__(256) void k_ehi(const float* __restrict__ embed,
                                             short* __restrict__ Eh) {
  const int t = threadIdx.x;
  const size_t row = blockIdx.x;
  float4 v = *(const float4*)(embed + row * CDIM + t * 4);
  *(short4*)(Eh + row * CDIM + t * 4) =
      make_short4((short)bf_rtn(v.x), (short)bf_rtn(v.y), (short)bf_rtn(v.z),
                  (short)bf_rtn(v.w));
}

// ---------------- K1: LN + GELU + @w_pre -> z fp32 + z bf16-hi ----------------
__global__ __launch_bounds__(256) void k_ln_gelu_gemm(
    const float* __restrict__ x, const float* __restrict__ ln_g,
    const float* __restrict__ ln_b, const float* __restrict__ w_pre,
    const float* __restrict__ b_pre, float* __restrict__ zf,
    short* __restrict__ zh, int row0) {
  __shared__ float g[16][DIMX];
  const int t = threadIdx.x;
  const int lrow0 = blockIdx.x * 16;
  const int grow0 = row0 + lrow0;
  const int wv = t >> 6, lane = t & 63;
#pragma unroll
  for (int j = 0; j < 4; ++j) {
    const int r = wv * 4 + j;
    const float* xr = x + (size_t)(grow0 + r) * DIMX;
    float4 v = *(const float4*)(xr + lane * 4);
    float s = v.x + v.y + v.z + v.w;
    float ss = v.x * v.x + v.y * v.y + v.z * v.z + v.w * v.w;
#pragma unroll
    for (int o = 32; o > 0; o >>= 1) { s += __shfl_xor(s, o); ss += __shfl_xor(ss, o); }
    const float mu = s * (1.0f / 256.0f);
    const float var = ss * (1.0f / 256.0f) - mu * mu;
    const float rstd = rsqrtf(var + 1e-5f);
    float vv[4] = {v.x, v.y, v.z, v.w};
#pragma unroll
    for (int q = 0; q < 4; ++q) {
      const int d = lane * 4 + q;
      float xn = (vv[q] - mu) * rstd * ln_g[d] + ln_b[d];
      g[r][d] = 0.5f * xn * (1.0f + erff(xn * 0.70710678118654752f));
    }
  }
  __syncthreads();
  float acc[16][4];
#pragma unroll
  for (int r = 0; r < 16; ++r)
#pragma unroll
    for (int c = 0; c < 4; ++c) acc[r][c] = 0.f;
#pragma unroll 4
  for (int d = 0; d < DIMX; ++d) {
    float4 w = *(const float4*)(w_pre + (size_t)d * CDIM + t * 4);
#pragma unroll
    for (int r = 0; r < 16; ++r) {
      const float gv = g[r][d];
      acc[r][0] = fmaf(gv, w.x, acc[r][0]);
      acc[r][1] = fmaf(gv, w.y, acc[r][1]);
      acc[r][2] = fmaf(gv, w.z, acc[r][2]);
      acc[r][3] = fmaf(gv, w.w, acc[r][3]);
    }
  }
  float4 bp = *(const float4*)(b_pre + t * 4);
#pragma unroll
  for (int r = 0; r < 16; ++r) {
    float4 o;
    o.x = acc[r][0] + bp.x; o.y = acc[r][1] + bp.y;
    o.z = acc[r][2] + bp.z; o.w = acc[r][3] + bp.w;
    *(float4*)(zf + (size_t)(lrow0 + r) * CDIM + t * 4) = o;
    *(short4*)(zh + (size_t)(lrow0 + r) * CDIM + t * 4) =
        make_short4((short)bf_rtn(o.x), (short)bf_rtn(o.y), (short)bf_rtn(o.z),
                    (short)bf_rtn(o.w));
  }
}

// ---------------- K2: coarse 1x bf16 MFMA scorer + candidate collect --------
// grid = (chunk/256)*NSP ; block = 512 (8 waves: 2M x 4N)
// 4-buffer LDS ring (128KB), prefetch distance 3, counted vmcnt (T3+T4)
__global__ __launch_bounds__(512) void k_score(
    const short* __restrict__ Eh, const short* __restrict__ Zh,
    const float* __restrict__ e_sq, uint2* __restrict__ cand, int chunk) {
  __shared__ __align__(16) short lds[4][16384];
  const int t = threadIdx.x;
  const int cpx = gridDim.x >> 3;  // bijective XCD swizzle, grid % 8 == 0
  const int bx = (blockIdx.x & 7) * cpx + (blockIdx.x >> 3);
  const int zblk = bx / NSP, csp = bx % NSP;
  const int wid = t >> 6, l = t & 63;
  const int wr = wid >> 2, wc = wid & 3;
  const int lg = l >> 4, lo16 = l & 15;
  const int rowbase = zblk * 256;
  const int m0 = csp * 256;
  const int wr8 = wr * 8, wc4 = wc * 4, l8 = l * 8;

  const bool isA = (wid < 4);
  const int q = wid & 3;
  const short* sarr = isA ? Eh : Zh;
  const int sbase = isA ? m0 : rowbase;
  const short* sp0 = sarr + (size_t)(sbase + q * 64 + lo16) * 1024 + lg * 8;
  const int dstbase = (isA ? 0 : 8192) + q * 4 * 512;

  f32x4 acc[8][4];
#pragma unroll
  for (int mi = 0; mi < 8; ++mi)
#pragma unroll
    for (int ni = 0; ni < 4; ++ni) acc[mi][ni] = (f32x4){0.f, 0.f, 0.f, 0.f};

  // prologue: issue loads for kt=0,1,2 (12 loads in flight per wave)
#pragma unroll
  for (int pk = 0; pk < 3; ++pk) {
    const short* sp = sp0 + pk * 32;
    short* D = &lds[pk][dstbase];
#pragma unroll
    for (int u = 0; u < 4; ++u) GLOAD_LDS16(sp + u * 16384, D + u * 512);
  }

#define SCORE_KT(KT, VMC, ST)                                                  \
  {                                                                            \
    const short* Lc = lds[(KT) & 3];                                           \
    wait_vm<VMC>();                                                            \
    __builtin_amdgcn_s_barrier();                                              \
    __builtin_amdgcn_sched_barrier(0);                                         \
    bf16x8 bh[4], a[8];                                                        \
    _Pragma("unroll") for (int ni = 0; ni < 4; ++ni) bh[ni] =                  \
        *(const bf16x8*)(Lc + 8192 + (wc4 + ni) * 512 + l8);                   \
    _Pragma("unroll") for (int u = 0; u < 8; ++u) a[u] =                       \
        *(const bf16x8*)(Lc + (wr8 + u) * 512 + l8);                           \
    if (ST) {                                                                  \
      short* Dst = &lds[((KT) + 3) & 3][dstbase];                              \
      const short* spk = sp0 + ((KT) + 3) * 32;                                \
      _Pragma("unroll") for (int u = 0; u < 4; ++u)                            \
          GLOAD_LDS16(spk + u * 16384, Dst + u * 512);                         \
    }                                                                          \
    asm volatile("s_waitcnt lgkmcnt(0)" ::: "memory");                         \
    __builtin_amdgcn_sched_barrier(0);                                         \
    __builtin_amdgcn_s_setprio(1);                                             \
    _Pragma("unroll") for (int u = 0; u < 8; ++u)                              \
        _Pragma("unroll") for (int ni = 0; ni < 4; ++ni) acc[u][ni] =          \
            __builtin_amdgcn_mfma_f32_16x16x32_bf16(a[u], bh[ni],              \
                                                    acc[u][ni], 0, 0, 0);      \
    __builtin_amdgcn_s_setprio(0);                                             \
  }

  for (int kt = 0; kt < 30; ++kt) SCORE_KT(kt, 8, (kt < 29));
  SCORE_KT(30, 4, false);
  SCORE_KT(31, 0, false);
#undef SCORE_KT

  // ---- epilogue: strip-min + candidate collect ----
  float s1[4];
  int i1[4];
#pragma unroll
  for (int i = 0; i < 4; ++i) { s1[i] = FLT_BIG; i1[i] = 0x7fffffff; }
#pragma unroll
  for (int mi = 0; mi < 8; ++mi) {
    const int c0 = m0 + wr * 128 + mi * 16 + lg * 4;
    float4 es = *(const float4*)(e_sq + c0);
    float esv[4] = {es.x, es.y, es.z, es.w};
#pragma unroll
    for (int ni = 0; ni < 4; ++ni) {
#pragma unroll
      for (int j = 0; j < 4; ++j) {
        const float s = fmaf(-2.0f, acc[mi][ni][j], esv[j]);
        const int c = c0 + j;
        if (s < s1[ni] || (s == s1[ni] && c < i1[ni])) { s1[ni] = s; i1[ni] = c; }
      }
    }
  }

  unsigned long long* red = (unsigned long long*)&lds[0][0];      // 512 u64
  float* sb = (float*)&lds[0][2048];                              // 256 f32
  unsigned* sbi = (unsigned*)&lds[0][2560];                       // 256 u32
  unsigned* cnt = (unsigned*)&lds[0][3072];                       // 256 u32
  uint2* slot = (uint2*)&lds[0][3584];                            // 256*3

  __syncthreads();
#pragma unroll
  for (int ni = 0; ni < 4; ++ni) {
    unsigned long long k1v =
        (((unsigned long long)fkey(s1[ni])) << 32) | (unsigned)i1[ni];
    unsigned long long o1 = __shfl_xor(k1v, 16);
    k1v = o1 < k1v ? o1 : k1v;
    o1 = __shfl_xor(k1v, 32);
    k1v = o1 < k1v ? o1 : k1v;
    if (lg == 0) {
      const int r = wc * 64 + ni * 16 + lo16;
      red[r * 2 + wr] = k1v;
    }
  }
  __syncthreads();
  if (t < 256) {
    unsigned long long a1 = red[t * 2 + 0], b1 = red[t * 2 + 1];
    if (b1 < a1) a1 = b1;
    sb[t] = keyinv((unsigned)(a1 >> 32));
    sbi[t] = (unsigned)(a1 & 0xFFFFFFFFull);
    cnt[t] = 0;
  }
  __syncthreads();
#pragma unroll
  for (int mi = 0; mi < 8; ++mi) {
    const int c0 = m0 + wr * 128 + mi * 16 + lg * 4;
    float4 es = *(const float4*)(e_sq + c0);
    float esv[4] = {es.x, es.y, es.z, es.w};
#pragma unroll
    for (int ni = 0; ni < 4; ++ni) {
      const int r = wc * 64 + ni * 16 + lo16;
      const float thr = sb[r] + CMARG;
#pragma unroll
      for (int j = 0; j < 4; ++j) {
        const float s = fmaf(-2.0f, acc[mi][ni][j], esv[j]);
        const unsigned c = (unsigned)(c0 + j);
        if (s < thr && c != sbi[r]) {
          unsigned pos = atomicAdd(&cnt[r], 1u);
          if (pos < 3) slot[r * 3 + pos] = make_uint2(__float_as_uint(s), c);
        }
      }
    }
  }
  __syncthreads();
  if (t < 256) {
    // row-major: 64 contiguous entries per row (16 strips x 4 slots)
    uint2* g = cand + ((size_t)(rowbase + t) * NSP + csp) * 4;
    const unsigned ov = (cnt[t] > 3) ? 0x40000000u : 0u;
    g[0] = make_uint2(__float_as_uint(sb[t]), sbi[t] | ov);
    const unsigned n = cnt[t] > 3 ? 3 : cnt[t];
#pragma unroll
    for (int k = 0; k < 3; ++k)
      g[1 + k] = (k < (int)n) ? slot[t * 3 + k]
                              : make_uint2(__float_as_uint(FLT_BIG), 0xFFFFFFFFu);
  }
}

// ---------------- K3: exact f64 refine on fp32 z over candidates ------------
__global__ __launch_bounds__(256) void k_refine(
    const uint2* __restrict__ cand, const float* __restrict__ zf,
    const float* __restrict__ embed, int* __restrict__ idxf,
    float* __restrict__ crow, float* __restrict__ out_idx,
    int* __restrict__ flag_rows, int* __restrict__ nflag, int chunk,
    int row0) {
  const int t = threadIdx.x, wid = t >> 6, l = t & 63;
  const int lrow = blockIdx.x * 4 + wid;
  if (lrow >= chunk) return;
  const int grow = row0 + lrow;
  // lane l holds candidate entry l (strip l>>2, slot l&3), 512B contiguous
  const uint2 cs = cand[(size_t)lrow * 64 + l];
  const float sc = __uint_as_float(cs.x);
  const unsigned raw = cs.y;
  const bool isMin = (l & 3) == 0;
  float gm = isMin ? sc : FLT_BIG;
#pragma unroll
  for (int o = 32; o > 0; o >>= 1) gm = fminf(gm, __shfl_xor(gm, o));
  const float thr = gm + RMARG;
  const bool ovf = __any(isMin && (raw & 0x40000000u) && (sc < thr));

  float zv[16];
#pragma unroll
  for (int j = 0; j < 16; ++j) zv[j] = zf[(size_t)lrow * CDIM + l + 64 * j];

  const int myidx = (int)(raw & 0xFFFFu);
  const bool valid = (sc < thr) && (myidx < KCODES);
  unsigned long long mask = __ballot(valid);
  double d1 = 1e300;
  int i1 = 0x7fffffff;
  while (mask) {
    const int src = __ffsll((unsigned long long)mask) - 1;
    mask &= mask - 1;
    const int c = __shfl(myidx, src);
    const float* e = embed + (size_t)c * CDIM;
    double dd = 0.0;
#pragma unroll
    for (int j = 0; j < 16; ++j) {
      const double df = (double)zv[j] - (double)e[l + 64 * j];
      dd = fma(df, df, dd);
    }
#pragma unroll
    for (int o = 32; o > 0; o >>= 1) dd += __shfl_xor(dd, o);
    if (dd < d1 || (dd == d1 && c < i1)) { d1 = dd; i1 = c; }
  }
  if (l == 0) {
    idxf[grow] = i1;
    out_idx[grow] = (float)i1;
    crow[grow] = (float)d1;
    if (ovf) {
      const int s = atomicAdd(nflag, 1);
      flag_rows[s] = lrow;
    }
  }
}

// ---------------- K3b: exact f64 full rescan (overflow rows only) -----------
__global__ __launch_bounds__(256) void k_exact(
    const float* __restrict__ zf, const float* __restrict__ embed,
    const int* __restrict__ flag_rows, const int* __restrict__ nflag,
    int* __restrict__ idxf, float* __restrict__ crow,
    float* __restrict__ out_idx, int row0) {
  __shared__ double wd[4];
  __shared__ int wcidx[4];
  const int t = threadIdx.x;
  const int wid = t >> 6, l = t & 63;
  const int n = *nflag;

  for (int fi = blockIdx.x; fi < n; fi += gridDim.x) {
    const int lrow = flag_rows[fi];
    const int grow = row0 + lrow;
    float zr[16];
#pragma unroll
    for (int j = 0; j < 16; ++j) zr[j] = zf[(size_t)lrow * CDIM + l + 64 * j];
    double dmin = 1e300;
    int cmin = 0x7fffffff;
    for (int ci = 0; ci < 1024; ++ci) {
      const int c = wid * 1024 + ci;
      const float* e = embed + (size_t)c * CDIM;
      double dd = 0.0;
#pragma unroll
      for (int j = 0; j < 16; ++j) {
        const double df = (double)zr[j] - (double)e[l + 64 * j];
        dd = fma(df, df, dd);
      }
#pragma unroll
      for (int o = 32; o > 0; o >>= 1) dd += __shfl_xor(dd, o);
      if (dd < dmin) { dmin = dd; cmin = c; }
    }
    if (l == 0) { wd[wid] = dmin; wcidx[wid] = cmin; }
    __syncthreads();
    if (t == 0) {
      double dm = wd[0]; int cm = wcidx[0];
#pragma unroll
      for (int wv = 1; wv < 4; ++wv) {
        if (wd[wv] < dm || (wd[wv] == dm && wcidx[wv] < cm)) {
          dm = wd[wv]; cm = wcidx[wv];
        }
      }
      idxf[grow] = cm;
      out_idx[grow] = (float)cm;
      crow[grow] = (float)dm;
    }
    __syncthreads();
  }
}

// ---------------- K4: E_post = embed @ w_post ----------------
__global__ __launch_bounds__(256) void k_epost(const float* __restrict__ E,
                                               const float* __restrict__ w_post,
                                               float* __restrict__ E_post) {
  __shared__ float es[16][128];
  const int t = threadIdx.x;
  const int r0 = blockIdx.x * 16;
  float acc[16];
#pragma unroll
  for (int r = 0; r < 16; ++r) acc[r] = 0.f;
  for (int k0 = 0; k0 < CDIM; k0 += 128) {
    __syncthreads();
#pragma unroll
    for (int p = 0; p < 2; ++p) {
      const int fl = (p * 256 + t) * 4;
      const int r = fl >> 7, kk = fl & 127;
      float4 v = *(const float4*)(E + (size_t)(r0 + r) * CDIM + k0 + kk);
      *(float4*)&es[r][kk] = v;
    }
    __syncthreads();
#pragma unroll 4
    for (int d = 0; d < 128; ++d) {
      const float w = w_post[(size_t)(k0 + d) * DIMX + t];
#pragma unroll
      for (int r = 0; r < 16; ++r) acc[r] = fmaf(es[r][d], w, acc[r]);
    }
  }
#pragma unroll
  for (int r = 0; r < 16; ++r)
    E_post[(size_t)(r0 + r) * DIMX + t] = acc[r];
}

// ---------------- K5: gather E_post rows + bias ----------------
__global__ __launch_bounds__(256) void k_gather(const float* __restrict__ E_post,
                                                const int* __restrict__ idx,
                                                const float* __restrict__ b_post,
                                                float* __restrict__ outq) {
  const int t = threadIdx.x;
  const int r0 = blockIdx.x * 16;
  const float bp = b_post[t];
#pragma unroll
  for (int i = 0; i < 16; ++i) {
    const int row = r0 + i;
    outq[(size_t)row * DIMX + t] = E_post[(size_t)idx[row] * DIMX + t] + bp;
  }
}

// ---------------- K6: commit reduce ----------------
__global__ __launch_bounds__(256) void k_commit_final(
    const float* __restrict__ crow, float* __restrict__ out_commit) {
  const int t = threadIdx.x;
  double s = 0.0;
  for (int i = t; i < BN_ROWS; i += 256) s += (double)crow[i];
#pragma unroll
  for (int o = 32; o > 0; o >>= 1) s += __shfl_xor(s, o);
  __shared__ double wsum[4];
  if ((t & 63) == 0) wsum[t >> 6] = s;
  __syncthreads();
  if (t == 0)
    *out_commit = (float)(0.25 * (wsum[0] + wsum[1] + wsum[2] + wsum[3]) /
                          (65536.0 * 1024.0));
}

extern "C" void kernel_launch(void* const* d_in, const int* in_sizes, int n_in,
                              void* d_out, int out_size, void* d_ws,
                              size_t ws_size, hipStream_t stream) {
  const float* x = (const float*)d_in[0];
  const float* ln_g = (const float*)d_in[1];
  const float* ln_b = (const float*)d_in[2];
  const float* w_pre = (const float*)d_in[3];
  const float* b_pre = (const float*)d_in[4];
  const float* embed = (const float*)d_in[5];
  const float* w_post = (const float*)d_in[6];
  const float* b_post = (const float*)d_in[7];

  float* out = (float*)d_out;
  float* outq = out;                   // 16777216 f32
  float* out_idx = out + 16777216;     // 65536 f32
  float* out_commit = out + 16842752;  // 1 f32

  char* ws = (char*)d_ws;
  float* e_sq = (float*)(ws + OFF_ESQ);
  int* idxf = (int*)(ws + OFF_IDXF);
  float* crow = (float*)(ws + OFF_CROW);
  float* E_post = (float*)(ws + OFF_EPOST);
  short* Eh = (short*)(ws + OFF_EH);
  int* nflag = (int*)(ws + OFF_NFLAG);
  int* flag_rows = (int*)(ws + OFF_FLAG);

  // chunk rows sized to ws: per-row = 512B (cand) + 2048B (zh) + 4096B (zf)
  int chunk = 4096;
  while (chunk < BN_ROWS &&
         OFF_CAND + (size_t)(chunk * 2) * 6656ull <= ws_size)
    chunk *= 2;
  uint2* cand = (uint2*)(ws + OFF_CAND);
  short* zh = (short*)(ws + OFF_CAND + (size_t)chunk * 512);
  float* zf = (float*)(ws + OFF_CAND + (size_t)chunk * 512 + (size_t)chunk * 2048);

  k_esq<<<KCODES / 4, 256, 0, stream>>>(embed, e_sq);
  k_ehi<<<KCODES, 256, 0, stream>>>(embed, Eh);
  k_epost<<<KCODES / 16, 256, 0, stream>>>(embed, w_post, E_post);

  for (int row0 = 0; row0 < BN_ROWS; row0 += chunk) {
    hipMemsetAsync(nflag, 0, sizeof(int), stream);
    k_ln_gelu_gemm<<<chunk / 16, 256, 0, stream>>>(x, ln_g, ln_b, w_pre, b_pre,
                                                   zf, zh, row0);
    k_score<<<(chunk / 256) * NSP, 512, 0, stream>>>(Eh, zh, e_sq, cand, chunk);
    k_refine<<<chunk / 4, 256, 0, stream>>>(cand, zf, embed, idxf, crow,
                                            out_idx, flag_rows, nflag, chunk,
                                            row0);
    k_exact<<<128, 256, 0, stream>>>(zf, embed, flag_rows, nflag, idxf, crow,
                                     out_idx, row0);
  }

  k_gather<<<BN_ROWS / 16, 256, 0, stream>>>(E_post, idxf, b_post, outq);
  k_commit_final<<<1, 256, 0, stream>>>(crow, out_commit);
}